// Round 10
// baseline (196.508 us; speedup 1.0000x reference)
//
#include <hip/hip_runtime.h>

typedef _Float16 h8 __attribute__((ext_vector_type(8)));
typedef _Float16 h4 __attribute__((ext_vector_type(4)));
typedef float f32x4 __attribute__((ext_vector_type(4)));

union HU { _Float16 h; unsigned short u; };
__device__ __forceinline__ unsigned short f2h(float f) { HU x; x.h = (_Float16)f; return x.u; }
__device__ __forceinline__ float h2f(unsigned short u) { HU x; x.u = u; return (float)x.h; }

#define MFMA16(a, b, c) __builtin_amdgcn_mfma_f32_16x16x32_f16((a), (b), (c), 0, 0, 0)

// ---------------------------------------------------------------------------
// k_prep: byte-identical to rounds 11/18/19 (w2f in 16x16 two-oc-tile packing).
// ---------------------------------------------------------------------------
__global__ void k_prep(const float* __restrict__ w1, const float* __restrict__ w2,
                       const float* __restrict__ w3,
                       const float* __restrict__ ptw1, const float* __restrict__ cfw1,
                       const float* __restrict__ ptw2, const float* __restrict__ ptw3,
                       const float* __restrict__ cfw2,
                       unsigned short* __restrict__ w1f,
                       unsigned short* __restrict__ w2f,
                       unsigned short* __restrict__ w3f,
                       unsigned short* __restrict__ w1hd,
                       unsigned short* __restrict__ w2hd,
                       unsigned short* __restrict__ w3hd) {
    int gid = blockIdx.x * 256 + threadIdx.x;
    int gs = gridDim.x * 256;
    for (int e = gid; e < 1024; e += gs) {
        int f = e >> 9, lane = (e >> 3) & 63, j = e & 7;
        int k = ((lane >> 4) << 3) + j, oc = lane & 15;
        int r, within;
        if (f == 0) { r = k >> 4; within = k & 15; }
        else        { r = 2;      within = k; }
        int tx = within >> 2, ch = within & 3;
        float v = 0.f;
        if (tx < 3 && ch < 3) v = w1[oc * 27 + ch * 9 + r * 3 + tx];
        w1f[e] = f2h(v);
    }
    for (int e = gid; e < 9216; e += gs) {
        int j = e & 7, lane = (e >> 3) & 63, fo = e >> 9;   // fo = t*2+ot
        int ot = fo & 1, t = fo >> 1;
        int k = ((lane >> 4) * 8) + j, oc = ot * 16 + (lane & 15);
        float v = (k < 16) ? w2[oc * 144 + k * 9 + t] : 0.f;
        w2f[e] = f2h(v);
    }
    for (int e = gid; e < 18432; e += gs) {
        int j = e & 7, lane = (e >> 3) & 63, fo = e >> 9;   // fo = (otp*9+t)*2+oti
        int oti = fo & 1, t = (fo >> 1) % 9, otp = (fo >> 1) / 9;
        int ic = ((lane >> 4) * 8) + j, oc = (otp * 2 + oti) * 16 + (lane & 15);
        w3f[e] = f2h(w3[oc * 288 + ic * 9 + t]);
    }
    for (int s = gid; s < 608 * 192; s += gs) {
        int k = s / 192, n = s - k * 192;
        float v = 0.f;
        if (k < 584) {
            int f = (k < 576) ? ((k & 63) * 9 + (k >> 6)) : k;
            v = (n < 128) ? ptw1[f * 128 + n] : cfw1[f * 64 + (n - 128)];
        }
        int kk = k >> 5, hi = (k & 31) >> 3, j = k & 7, nt = n >> 4;
        int e = (((kk * 12 + nt) << 6) | (hi << 4) | (n & 15)) << 3 | j;
        w1hd[e] = f2h(v);
    }
    for (int s = gid; s < 8192; s += gs) {
        int k = s >> 6, n = s & 63;
        float v = ptw2[k * 64 + n];
        int kk = k >> 5, hi = (k & 31) >> 3, j = k & 7, nt = n >> 4;
        int e = ((((kk << 2) | nt) << 6) | (hi << 4) | (n & 15)) << 3 | j;
        w2hd[e] = f2h(v);
    }
    for (int e = gid; e < 2048; e += gs) {
        int j = e & 7, lane = (e >> 3) & 63, kk = e >> 9;
        int k = kk * 32 + ((lane >> 4) * 8) + j, n = lane & 15;
        float v = 0.f;
        if (k < 64) { if (n < 2) v = ptw3[k * 2 + n]; }
        else        { if (n == 2) v = cfw2[k - 64]; }
        w3hd[e] = f2h(v);
    }
}

// ---------------------------------------------------------------------------
// k_fused, round 22: r19 (82.5 us, best validated) + LDS bank-conflict
// padding. All per-lane col*stride reads had dword-strides = {4,20} mod 32
// (gcd 4 -> 8 banks for 16 lanes). +4-half pads make strides = {6,22} mod 32
// (gcd 2 -> 16 distinct banks): A1S 588, A2S 300, FTS 620, HSH 204.
// SQ_LDS_BANK_CONFLICT 3.67M -> expect <1.5M. LDS 53248 B, still 3 blocks/CU.
// Wave structure fixed at 4w/3blk: measured optimum (1w=230, 2w=110, 8w=100).
// ---------------------------------------------------------------------------
#define BDS4 260
#define A1S 588
#define A2S 300
#define FTS 620
#define HSH 204
#define RA_OFF 19840
#define O_OFF 26368
#define LDSTOT 26624

__global__ __launch_bounds__(256, 3) void k_fused(
    const float* __restrict__ board,
    const float* __restrict__ b1, const float* __restrict__ b2,
    const float* __restrict__ b3, const float* __restrict__ qp,
    const unsigned short* __restrict__ w1f,
    const unsigned short* __restrict__ w2f,
    const unsigned short* __restrict__ w3f,
    const unsigned short* __restrict__ w1hd,
    const unsigned short* __restrict__ w2hd,
    const unsigned short* __restrict__ w3hd,
    const float* __restrict__ ptb1, const float* __restrict__ ptb2,
    const float* __restrict__ ptb3, const float* __restrict__ cfb1,
    const float* __restrict__ cfb2,
    float* __restrict__ out)
{
    __shared__ __align__(16) unsigned short LDSH[LDSTOT];
    const int tid = threadIdx.x, wid = tid >> 6, lane = tid & 63;
    const int g = wid >> 1, w2 = wid & 1;
    const int col = lane & 15, q = lane >> 4;
    const long long gg0 = (long long)blockIdx.x * 32;
    const f32x4 ZERO4 = {0.f, 0.f, 0.f, 0.f};

    unsigned short* A1 = LDSH + g * 9856;
    unsigned short* A2 = A1;                          // overlay (barriered)
    unsigned short* Hb = LDSH + RA_OFF;               // overlays BD (dead)
    float* O = (float*)(LDSH + O_OFF);

    // ---- 0. issue board preloads (both groups) + quantum global loads ----
    const f32x4* bp4 = (const f32x4*)(board + gg0 * 108);
    f32x4 v0a = bp4[tid];                 // g0
    f32x4 v0b = ZERO4, v1b = ZERO4;
    if (tid < 176) v0b = bp4[tid + 256];
    f32x4 v1a = bp4[tid + 432];           // g1
    if (tid < 176) v1b = bp4[tid + 688];

    float xq0 = 0.f, xn0 = 0.f, xq1 = 0.f, xn1 = 0.f;
    if (tid < 128) {
        int ss = tid >> 3, qq = tid & 7, e2 = (qq + 1) & 7;
        const float* b0p = board + (gg0 + ss) * 108;
        xq0 = b0p[qq];  xn0 = b0p[e2];
        xq1 = b0p[16 * 108 + qq];  xn1 = b0p[16 * 108 + e2];
    }

    // ---- 1. stage g0 + zero halo/ch3/spare (disjoint writes, one phase) ----
    {
        if (tid < 128) {
            int ss = tid >> 3, row = tid & 7;
            unsigned long long* Z =
                (unsigned long long*)&LDSH[RA_OFF + ss * BDS4];
            if (row == 0) {
                #pragma unroll
                for (int i = 0; i < 8; i++) Z[i] = 0ULL;
            } else if (row == 7) {
                #pragma unroll
                for (int i = 56; i < 65; i++) Z[i] = 0ULL;   // row 7 + spares
            } else {
                Z[row * 8] = 0ULL;          // col 0 cell
                Z[row * 8 + 7] = 0ULL;      // col 7 cell
                #pragma unroll
                for (int c = 1; c < 7; c++) // interior ch3
                    LDSH[RA_OFF + ss * BDS4 + row * 32 + c * 4 + 3] = 0;
            }
        }
        int ss = tid / 27, r27 = tid - ss * 27, f0 = r27 * 4;
        #pragma unroll
        for (int j = 0; j < 4; j++) {
            int f = f0 + j, ch = f / 36, p = f - ch * 36;
            LDSH[RA_OFF + ss * BDS4 + ((p / 6 + 1) * 8 + (p % 6) + 1) * 4 + ch] =
                f2h(v0a[j]);
        }
        if (tid < 176) {
            int e4 = tid + 256;
            int ss2 = e4 / 27, r2 = e4 - ss2 * 27, f02 = r2 * 4;
            #pragma unroll
            for (int j = 0; j < 4; j++) {
                int f = f02 + j, ch = f / 36, p = f - ch * 36;
                LDSH[RA_OFF + ss2 * BDS4 + ((p / 6 + 1) * 8 + (p % 6) + 1) * 4 + ch] =
                    f2h(v0b[j]);
            }
        }
    }
    __syncthreads();

    // ---- 2. conv1 g0 (+ quantum chains on waves 0,1 — VALU overlaps MFMA) ----
    float qv0 = 0.f, qv1 = 0.f;
    h8 w1r0 = ((const h8*)w1f)[lane];
    h8 w1r1 = ((const h8*)w1f)[64 + lane];
    float b1v = b1[col];
    if (tid < 128) {
        int qq = tid & 7;
        float s0 = 0.f, s1 = 0.f;
        for (int l = 0; l < 3; l++) {
            float a0 = qp[l * 24 + qq * 3], a1 = qp[l * 24 + qq * 3 + 1],
                  a2 = qp[l * 24 + qq * 3 + 2];
            s0 = sinf(a0 * xq0) * cosf(a1 * xn0) + tanhf(a2 * s0);
            s1 = sinf(a0 * xq1) * cosf(a1 * xn1) + tanhf(a2 * s1);
        }
        qv0 = s0; qv1 = s1;
    }
    {
        unsigned short* A1g = LDSH;
        const int bs = RA_OFF + col * BDS4;
        const int rsel = q >> 1, wo = (q & 1) * 8;
        for (int p = wid * 9; p < wid * 9 + 9; p++) {
            int y = p / 6, x = p % 6;
            int ab1 = bs + ((y + rsel) * 8 + x) * 4 + wo;
            int ab2 = bs + ((y + 2) * 8 + x) * 4 + wo;
            union { h8 v; h4 h[2]; } a1v, a2v;
            a1v.h[0] = *(const h4*)&LDSH[ab1];
            a1v.h[1] = *(const h4*)&LDSH[ab1 + 4];
            a2v.h[0] = *(const h4*)&LDSH[ab2];
            a2v.h[1] = *(const h4*)&LDSH[ab2 + 4];
            f32x4 c = MFMA16(a1v.v, w1r0, ZERO4);
            c = MFMA16(a2v.v, w1r1, c);
            #pragma unroll
            for (int r = 0; r < 4; r++)
                A1g[(q * 4 + r) * A1S + p * 16 + col] =
                    f2h(fmaxf(c[r] + b1v, 0.f));
        }
    }
    __syncthreads();

    // ---- 3. stage g1 from registers (no HBM latency here) ----
    {
        int ss = tid / 27, r27 = tid - ss * 27, f0 = r27 * 4;
        #pragma unroll
        for (int j = 0; j < 4; j++) {
            int f = f0 + j, ch = f / 36, p = f - ch * 36;
            LDSH[RA_OFF + ss * BDS4 + ((p / 6 + 1) * 8 + (p % 6) + 1) * 4 + ch] =
                f2h(v1a[j]);
        }
        if (tid < 176) {
            int e4 = tid + 256;
            int ss2 = e4 / 27, r2 = e4 - ss2 * 27, f02 = r2 * 4;
            #pragma unroll
            for (int j = 0; j < 4; j++) {
                int f = f02 + j, ch = f / 36, p = f - ch * 36;
                LDSH[RA_OFF + ss2 * BDS4 + ((p / 6 + 1) * 8 + (p % 6) + 1) * 4 + ch] =
                    f2h(v1b[j]);
            }
        }
    }
    __syncthreads();

    // ---- 4. conv1 g1 ----
    {
        unsigned short* A1g = LDSH + 9856;
        const int bs = RA_OFF + col * BDS4;
        const int rsel = q >> 1, wo = (q & 1) * 8;
        for (int p = wid * 9; p < wid * 9 + 9; p++) {
            int y = p / 6, x = p % 6;
            int ab1 = bs + ((y + rsel) * 8 + x) * 4 + wo;
            int ab2 = bs + ((y + 2) * 8 + x) * 4 + wo;
            union { h8 v; h4 h[2]; } a1v, a2v;
            a1v.h[0] = *(const h4*)&LDSH[ab1];
            a1v.h[1] = *(const h4*)&LDSH[ab1 + 4];
            a2v.h[0] = *(const h4*)&LDSH[ab2];
            a2v.h[1] = *(const h4*)&LDSH[ab2 + 4];
            f32x4 c = MFMA16(a1v.v, w1r0, ZERO4);
            c = MFMA16(a2v.v, w1r1, c);
            #pragma unroll
            for (int r = 0; r < 4; r++)
                A1g[(q * 4 + r) * A1S + p * 16 + col] =
                    f2h(fmaxf(c[r] + b1v, 0.f));
        }
    }
    __syncthreads();

    // ---- 5. conv2: read-once register rows; wave = oc-tile w2, all 36 pos ----
    f32x4 pooled2[9];
    #pragma unroll
    for (int pp = 0; pp < 9; pp++) pooled2[pp] = ZERO4;
    {
        h8 W2r[9];
        #pragma unroll
        for (int t = 0; t < 9; t++)
            W2r[t] = ((const h8*)w2f)[(t * 2 + w2) * 64 + lane];
        float b2v = b2[w2 * 16 + col];
        const int sA1 = col * A1S;
        const int kho = (q & 1) * 8;

        __builtin_amdgcn_s_setprio(1);
        h8 R[3][6];
        #pragma unroll
        for (int x = 0; x < 6; x++) {
            R[0][x] = *(const h8*)&A1[sA1 + (0 * 6 + x) * 16 + kho];
            R[1][x] = *(const h8*)&A1[sA1 + (1 * 6 + x) * 16 + kho];
        }
        #pragma unroll
        for (int y = 0; y < 6; y++) {
            if (y >= 1 && y <= 4) {
                const int nr = y + 1, slot = nr % 3;
                #pragma unroll
                for (int x = 0; x < 6; x++)
                    R[slot][x] = *(const h8*)&A1[sA1 + (nr * 6 + x) * 16 + kho];
            }
            f32x4 acc[6];
            #pragma unroll
            for (int x = 0; x < 6; x++) acc[x] = ZERO4;
            #pragma unroll
            for (int dy = -1; dy <= 1; dy++) {
                const int ry = y + dy;
                if (ry < 0 || ry > 5) continue;
                const int slot = ry % 3;
                #pragma unroll
                for (int x = 0; x < 6; x++)
                    #pragma unroll
                    for (int dx = -1; dx <= 1; dx++) {
                        const int sx = x + dx;
                        if (sx < 0 || sx > 5) continue;
                        acc[x] = MFMA16(R[slot][sx],
                                        W2r[(dy + 1) * 3 + (dx + 1)], acc[x]);
                    }
            }
            const int pr = y >> 1;
            #pragma unroll
            for (int px = 0; px < 3; px++)
                #pragma unroll
                for (int xx = 0; xx < 2; xx++)
                    #pragma unroll
                    for (int r = 0; r < 4; r++)
                        pooled2[pr * 3 + px][r] =
                            fmaxf(pooled2[pr * 3 + px][r],
                                  acc[px * 2 + xx][r] + b2v);
        }
        __builtin_amdgcn_s_setprio(0);
    }
    __syncthreads();   // all A1 reads (block-wide) done before A2 overlays
    #pragma unroll
    for (int pp = 0; pp < 9; pp++)
        #pragma unroll
        for (int r = 0; r < 4; r++)
            A2[(q * 4 + r) * A2S + pp * 32 + w2 * 16 + col] =
                f2h(pooled2[pp][r]);
    __syncthreads();

    // ---- 6. conv3 -> registers (otp = w2) ----
    f32x4 c3a[9], c3b[9];
    {
        const int otp = w2;
        const int sA2 = col * A2S;
        h8 W3r[18];
        #pragma unroll
        for (int f = 0; f < 18; f++)
            W3r[f] = ((const h8*)w3f)[(otp * 18 + f) * 64 + lane];
        __builtin_amdgcn_s_setprio(1);
        #pragma unroll
        for (int p = 0; p < 9; p++) {
            const int y = p / 3, x = p % 3;
            f32x4 acc0 = ZERO4, acc1 = ZERO4;
            #pragma unroll
            for (int t = 0; t < 9; t++) {
                const int sy = y + t / 3 - 1, sx = x + t % 3 - 1;
                if (sy < 0 || sy >= 3 || sx < 0 || sx >= 3) continue;
                h8 a = *(const h8*)&A2[sA2 + (sy * 3 + sx) * 32 + q * 8];
                acc0 = MFMA16(a, W3r[t * 2 + 0], acc0);
                acc1 = MFMA16(a, W3r[t * 2 + 1], acc1);
            }
            c3a[p] = acc0; c3b[p] = acc1;
        }
        __builtin_amdgcn_s_setprio(0);
    }
    __syncthreads();   // all A2 reads done before FT overlays region

    // ---- 7. write FT [p][oc] + quantum + zero tail cols 584..607 ----
    {
        const int otp = w2;
        float b3v0 = b3[(otp * 2 + 0) * 16 + col];
        float b3v1 = b3[(otp * 2 + 1) * 16 + col];
        int oc0 = (otp * 2 + 0) * 16 + col, oc1 = (otp * 2 + 1) * 16 + col;
        #pragma unroll
        for (int p = 0; p < 9; p++)
            #pragma unroll
            for (int r = 0; r < 4; r++) {
                int row = g * 16 + q * 4 + r;
                LDSH[row * FTS + p * 64 + oc0] = f2h(fmaxf(c3a[p][r] + b3v0, 0.f));
                LDSH[row * FTS + p * 64 + oc1] = f2h(fmaxf(c3b[p][r] + b3v1, 0.f));
            }
        if (tid < 128) {
            int ss = tid >> 3, qq = tid & 7;
            LDSH[ss * FTS + 576 + qq] = f2h(qv0);
            LDSH[(ss + 16) * FTS + 576 + qq] = f2h(qv1);
        }
        for (int e = tid; e < 1024; e += 256)
            LDSH[(e >> 5) * FTS + 584 + (e & 31)] = 0;
    }
    __syncthreads();

    // ---- 8. heads L1: K=608 (19 kk), wave does nt-tiles wid*3..+2, both mt ----
    {
        f32x4 acc[2][3];
        #pragma unroll
        for (int mt = 0; mt < 2; mt++)
            #pragma unroll
            for (int nt = 0; nt < 3; nt++) acc[mt][nt] = ZERO4;
        const h8* wp1 = (const h8*)w1hd;
        const int ntb = wid * 3;
        __builtin_amdgcn_s_setprio(1);
        for (int kk = 0; kk < 19; kk++) {
            h8 a0 = *(const h8*)&LDSH[col * FTS + kk * 32 + q * 8];
            h8 a1 = *(const h8*)&LDSH[(16 + col) * FTS + kk * 32 + q * 8];
            h8 b[3];
            #pragma unroll
            for (int nt = 0; nt < 3; nt++)
                b[nt] = wp1[(kk * 12 + ntb + nt) * 64 + lane];
            #pragma unroll
            for (int nt = 0; nt < 3; nt++) {
                acc[0][nt] = MFMA16(a0, b[nt], acc[0][nt]);
                acc[1][nt] = MFMA16(a1, b[nt], acc[1][nt]);
            }
        }
        __builtin_amdgcn_s_setprio(0);
        #pragma unroll
        for (int nt = 0; nt < 3; nt++) {
            int ntg = ntb + nt;
            float bv = (ntg < 8) ? ptb1[ntg * 16 + col] : cfb1[(ntg - 8) * 16 + col];
            #pragma unroll
            for (int mt = 0; mt < 2; mt++)
                #pragma unroll
                for (int r = 0; r < 4; r++)
                    Hb[(mt * 16 + q * 4 + r) * HSH + ntg * 16 + col] =
                        f2h(fmaxf(acc[mt][nt][r] + bv, 0.f));
        }
    }
    __syncthreads();

    // ---- 9. heads L2: nt = wid, both mt; output -> dead FT region (base 0,
    //      stride HSH) so Hb is never overwritten: no pre-write barrier ----
    {
        f32x4 acc2[2];
        acc2[0] = ZERO4; acc2[1] = ZERO4;
        const h8* wp2 = (const h8*)w2hd;
        const int nt2 = wid;
        #pragma unroll
        for (int kk = 0; kk < 4; kk++) {
            h8 a0 = *(const h8*)&Hb[col * HSH + kk * 32 + q * 8];
            h8 a1 = *(const h8*)&Hb[(16 + col) * HSH + kk * 32 + q * 8];
            h8 b = wp2[(kk * 4 + nt2) * 64 + lane];
            acc2[0] = MFMA16(a0, b, acc2[0]);
            acc2[1] = MFMA16(a1, b, acc2[1]);
        }
        float bv2 = ptb2[nt2 * 16 + col];
        #pragma unroll
        for (int mt = 0; mt < 2; mt++)
            #pragma unroll
            for (int r = 0; r < 4; r++)
                LDSH[(mt * 16 + q * 4 + r) * HSH + nt2 * 16 + col] =
                    f2h(fmaxf(acc2[mt][r] + bv2, 0.f));
    }
    __syncthreads();

    // ---- 10. heads L3 + epilogue: waves 0,1 handle mt = wid ----
    if (wid < 2) {
        const int mt = wid;
        f32x4 a3 = ZERO4;
        #pragma unroll
        for (int kk = 0; kk < 4; kk++) {
            // kk 0,1: pt-L2 output (FT region); kk 2,3: cf-L1 output (Hb)
            h8 a = (kk < 2)
                ? *(const h8*)&LDSH[(mt * 16 + col) * HSH + kk * 32 + q * 8]
                : *(const h8*)&Hb[(mt * 16 + col) * HSH + kk * 32 + 64 + q * 8];
            h8 b = ((const h8*)w3hd)[kk * 64 + lane];
            a3 = MFMA16(a, b, a3);
        }
        if (col < 3) {
            float bv = (col < 2) ? ptb3[col] : cfb2[0];
            #pragma unroll
            for (int r = 0; r < 4; r++)
                O[(mt * 16 + q * 4 + r) * 4 + col] = a3[r] + bv;
        }
        if (lane < 16) {
            int s = mt * 16 + lane;
            float l0 = O[s * 4 + 0], l1 = O[s * 4 + 1], l2 = O[s * 4 + 2];
            float m = fmaxf(l0, l1);
            float e0 = expf(l0 - m), e1 = expf(l1 - m);
            float inv = 1.f / (e0 + e1);
            float* op = out + (gg0 + s) * 3;
            op[0] = e0 * inv;
            op[1] = e1 * inv;
            op[2] = 1.f / (1.f + expf(-l2));
        }
    }
}

extern "C" void kernel_launch(void* const* d_in, const int* in_sizes, int n_in,
                              void* d_out, int out_size, void* d_ws, size_t ws_size,
                              hipStream_t stream) {
    const float* board = (const float*)d_in[0];
    const float* c1w  = (const float*)d_in[2];
    const float* c1b  = (const float*)d_in[3];
    const float* c2w  = (const float*)d_in[4];
    const float* c2b  = (const float*)d_in[5];
    const float* c3w  = (const float*)d_in[6];
    const float* c3b  = (const float*)d_in[7];
    const float* qp   = (const float*)d_in[8];
    const float* ptw1 = (const float*)d_in[9];
    const float* ptb1 = (const float*)d_in[10];
    const float* ptw2 = (const float*)d_in[11];
    const float* ptb2 = (const float*)d_in[12];
    const float* ptw3 = (const float*)d_in[13];
    const float* ptb3 = (const float*)d_in[14];
    const float* cfw1 = (const float*)d_in[15];
    const float* cfb1 = (const float*)d_in[16];
    const float* cfw2 = (const float*)d_in[17];
    const float* cfb2 = (const float*)d_in[18];
    float* out = (float*)d_out;

    int Btot = in_sizes[0] / 108;          // 65536

    unsigned short* w1f   = (unsigned short*)d_ws;
    unsigned short* w2f   = (unsigned short*)((char*)d_ws + 2048);
    unsigned short* w3f   = (unsigned short*)((char*)d_ws + 20480);
    unsigned short* w1hd  = (unsigned short*)((char*)d_ws + 57344);
    unsigned short* w2hd  = (unsigned short*)((char*)d_ws + 290816);
    unsigned short* w3hd  = (unsigned short*)((char*)d_ws + 307200);

    hipLaunchKernelGGL(k_prep, dim3(256), dim3(256), 0, stream,
                       c1w, c2w, c3w, ptw1, cfw1, ptw2, ptw3, cfw2,
                       w1f, w2f, w3f, w1hd, w2hd, w3hd);
    hipLaunchKernelGGL(k_fused, dim3(Btot / 32), dim3(256), 0, stream,
                       board, c1b, c2b, c3b, qp, w1f, w2f, w3f,
                       w1hd, w2hd, w3hd, ptb1, ptb2, ptb3, cfb1, cfb2, out);
}

// Round 11
// 172.050 us; speedup vs baseline: 1.1422x; 1.1422x over previous
//
#include <hip/hip_runtime.h>

typedef _Float16 h8 __attribute__((ext_vector_type(8)));
typedef _Float16 h4 __attribute__((ext_vector_type(4)));
typedef float f32x4 __attribute__((ext_vector_type(4)));

union HU { _Float16 h; unsigned short u; };
__device__ __forceinline__ unsigned short f2h(float f) { HU x; x.h = (_Float16)f; return x.u; }
__device__ __forceinline__ float h2f(unsigned short u) { HU x; x.u = u; return (float)x.h; }

#define MFMA16(a, b, c) __builtin_amdgcn_mfma_f32_16x16x32_f16((a), (b), (c), 0, 0, 0)

// ---------------------------------------------------------------------------
// k_prep: byte-identical to rounds 11/18/19 (w2f in 16x16 two-oc-tile packing).
// ---------------------------------------------------------------------------
__global__ void k_prep(const float* __restrict__ w1, const float* __restrict__ w2,
                       const float* __restrict__ w3,
                       const float* __restrict__ ptw1, const float* __restrict__ cfw1,
                       const float* __restrict__ ptw2, const float* __restrict__ ptw3,
                       const float* __restrict__ cfw2,
                       unsigned short* __restrict__ w1f,
                       unsigned short* __restrict__ w2f,
                       unsigned short* __restrict__ w3f,
                       unsigned short* __restrict__ w1hd,
                       unsigned short* __restrict__ w2hd,
                       unsigned short* __restrict__ w3hd) {
    int gid = blockIdx.x * 256 + threadIdx.x;
    int gs = gridDim.x * 256;
    for (int e = gid; e < 1024; e += gs) {
        int f = e >> 9, lane = (e >> 3) & 63, j = e & 7;
        int k = ((lane >> 4) << 3) + j, oc = lane & 15;
        int r, within;
        if (f == 0) { r = k >> 4; within = k & 15; }
        else        { r = 2;      within = k; }
        int tx = within >> 2, ch = within & 3;
        float v = 0.f;
        if (tx < 3 && ch < 3) v = w1[oc * 27 + ch * 9 + r * 3 + tx];
        w1f[e] = f2h(v);
    }
    for (int e = gid; e < 9216; e += gs) {
        int j = e & 7, lane = (e >> 3) & 63, fo = e >> 9;   // fo = t*2+ot
        int ot = fo & 1, t = fo >> 1;
        int k = ((lane >> 4) * 8) + j, oc = ot * 16 + (lane & 15);
        float v = (k < 16) ? w2[oc * 144 + k * 9 + t] : 0.f;
        w2f[e] = f2h(v);
    }
    for (int e = gid; e < 18432; e += gs) {
        int j = e & 7, lane = (e >> 3) & 63, fo = e >> 9;   // fo = (otp*9+t)*2+oti
        int oti = fo & 1, t = (fo >> 1) % 9, otp = (fo >> 1) / 9;
        int ic = ((lane >> 4) * 8) + j, oc = (otp * 2 + oti) * 16 + (lane & 15);
        w3f[e] = f2h(w3[oc * 288 + ic * 9 + t]);
    }
    for (int s = gid; s < 608 * 192; s += gs) {
        int k = s / 192, n = s - k * 192;
        float v = 0.f;
        if (k < 584) {
            int f = (k < 576) ? ((k & 63) * 9 + (k >> 6)) : k;
            v = (n < 128) ? ptw1[f * 128 + n] : cfw1[f * 64 + (n - 128)];
        }
        int kk = k >> 5, hi = (k & 31) >> 3, j = k & 7, nt = n >> 4;
        int e = (((kk * 12 + nt) << 6) | (hi << 4) | (n & 15)) << 3 | j;
        w1hd[e] = f2h(v);
    }
    for (int s = gid; s < 8192; s += gs) {
        int k = s >> 6, n = s & 63;
        float v = ptw2[k * 64 + n];
        int kk = k >> 5, hi = (k & 31) >> 3, j = k & 7, nt = n >> 4;
        int e = ((((kk << 2) | nt) << 6) | (hi << 4) | (n & 15)) << 3 | j;
        w2hd[e] = f2h(v);
    }
    for (int e = gid; e < 2048; e += gs) {
        int j = e & 7, lane = (e >> 3) & 63, kk = e >> 9;
        int k = kk * 32 + ((lane >> 4) * 8) + j, n = lane & 15;
        float v = 0.f;
        if (k < 64) { if (n < 2) v = ptw3[k * 2 + n]; }
        else        { if (n == 2) v = cfw2[k - 64]; }
        w3hd[e] = f2h(v);
    }
}

// ---------------------------------------------------------------------------
// k_fused, round 23 == round 19 verbatim (the validated best: 82.2-84.2 us).
// r22's +4-half bank-conflict pads broke 16B alignment of every h8 LDS row
// (584->588 halfs = 1168->1176 B) -> split ds_read_b64 pairs on all hot
// paths -> MfmaUtil 34->24, dur 82.5->112 us despite conflicts 3.67M->0.64M.
// 16B-aligned strides force gcd(stride_dw,32)>=4, so padding cannot fix the
// remaining ~7% conflict cost; alignment-preserving XOR swizzle is the only
// route and is bounded-gain/high-risk. Wave structure fixed at 4w/3blk
// (measured: 1w=230, 2w=110, 4w=82.5, 8w=100 us).
// ---------------------------------------------------------------------------
#define BDS4 260
#define A1S 584
#define A2S 296
#define FTS 616
#define HSH 200
#define RA_OFF 19712
#define O_OFF 26112
#define LDSTOT 26368

__global__ __launch_bounds__(256, 3) void k_fused(
    const float* __restrict__ board,
    const float* __restrict__ b1, const float* __restrict__ b2,
    const float* __restrict__ b3, const float* __restrict__ qp,
    const unsigned short* __restrict__ w1f,
    const unsigned short* __restrict__ w2f,
    const unsigned short* __restrict__ w3f,
    const unsigned short* __restrict__ w1hd,
    const unsigned short* __restrict__ w2hd,
    const unsigned short* __restrict__ w3hd,
    const float* __restrict__ ptb1, const float* __restrict__ ptb2,
    const float* __restrict__ ptb3, const float* __restrict__ cfb1,
    const float* __restrict__ cfb2,
    float* __restrict__ out)
{
    __shared__ __align__(16) unsigned short LDSH[LDSTOT];
    const int tid = threadIdx.x, wid = tid >> 6, lane = tid & 63;
    const int g = wid >> 1, w2 = wid & 1;
    const int col = lane & 15, q = lane >> 4;
    const long long gg0 = (long long)blockIdx.x * 32;
    const f32x4 ZERO4 = {0.f, 0.f, 0.f, 0.f};

    unsigned short* A1 = LDSH + g * 9856;
    unsigned short* A2 = A1;                          // overlay (barriered)
    unsigned short* Hb = LDSH + RA_OFF;               // overlays BD (dead)
    float* O = (float*)(LDSH + O_OFF);

    // ---- 0. issue board preloads (both groups) + quantum global loads ----
    const f32x4* bp4 = (const f32x4*)(board + gg0 * 108);
    f32x4 v0a = bp4[tid];                 // g0, e4 = tid (tid < 432 always)
    f32x4 v0b = ZERO4, v1b = ZERO4;
    if (tid < 176) v0b = bp4[tid + 256];
    f32x4 v1a = bp4[tid + 432];           // g1
    if (tid < 176) v1b = bp4[tid + 688];

    float xq0 = 0.f, xn0 = 0.f, xq1 = 0.f, xn1 = 0.f;
    if (tid < 128) {
        int ss = tid >> 3, qq = tid & 7, e2 = (qq + 1) & 7;
        const float* b0p = board + (gg0 + ss) * 108;
        xq0 = b0p[qq];  xn0 = b0p[e2];
        xq1 = b0p[16 * 108 + qq];  xn1 = b0p[16 * 108 + e2];
    }

    // ---- 1. stage g0 + zero halo/ch3/spare (disjoint writes, one phase) ----
    {
        if (tid < 128) {
            int ss = tid >> 3, row = tid & 7;
            unsigned long long* Z =
                (unsigned long long*)&LDSH[RA_OFF + ss * BDS4];
            if (row == 0) {
                #pragma unroll
                for (int i = 0; i < 8; i++) Z[i] = 0ULL;
            } else if (row == 7) {
                #pragma unroll
                for (int i = 56; i < 65; i++) Z[i] = 0ULL;   // row 7 + spares
            } else {
                Z[row * 8] = 0ULL;          // col 0 cell
                Z[row * 8 + 7] = 0ULL;      // col 7 cell
                #pragma unroll
                for (int c = 1; c < 7; c++) // interior ch3
                    LDSH[RA_OFF + ss * BDS4 + row * 32 + c * 4 + 3] = 0;
            }
        }
        int ss = tid / 27, r27 = tid - ss * 27, f0 = r27 * 4;
        #pragma unroll
        for (int j = 0; j < 4; j++) {
            int f = f0 + j, ch = f / 36, p = f - ch * 36;
            LDSH[RA_OFF + ss * BDS4 + ((p / 6 + 1) * 8 + (p % 6) + 1) * 4 + ch] =
                f2h(v0a[j]);
        }
        if (tid < 176) {
            int e4 = tid + 256;
            int ss2 = e4 / 27, r2 = e4 - ss2 * 27, f02 = r2 * 4;
            #pragma unroll
            for (int j = 0; j < 4; j++) {
                int f = f02 + j, ch = f / 36, p = f - ch * 36;
                LDSH[RA_OFF + ss2 * BDS4 + ((p / 6 + 1) * 8 + (p % 6) + 1) * 4 + ch] =
                    f2h(v0b[j]);
            }
        }
    }
    __syncthreads();

    // ---- 2. conv1 g0 (+ quantum chains on waves 0,1 — VALU overlaps MFMA) ----
    float qv0 = 0.f, qv1 = 0.f;
    h8 w1r0 = ((const h8*)w1f)[lane];
    h8 w1r1 = ((const h8*)w1f)[64 + lane];
    float b1v = b1[col];
    if (tid < 128) {
        int qq = tid & 7;
        float s0 = 0.f, s1 = 0.f;
        for (int l = 0; l < 3; l++) {
            float a0 = qp[l * 24 + qq * 3], a1 = qp[l * 24 + qq * 3 + 1],
                  a2 = qp[l * 24 + qq * 3 + 2];
            s0 = sinf(a0 * xq0) * cosf(a1 * xn0) + tanhf(a2 * s0);
            s1 = sinf(a0 * xq1) * cosf(a1 * xn1) + tanhf(a2 * s1);
        }
        qv0 = s0; qv1 = s1;
    }
    {
        unsigned short* A1g = LDSH;
        const int bs = RA_OFF + col * BDS4;
        const int rsel = q >> 1, wo = (q & 1) * 8;
        for (int p = wid * 9; p < wid * 9 + 9; p++) {
            int y = p / 6, x = p % 6;
            int ab1 = bs + ((y + rsel) * 8 + x) * 4 + wo;
            int ab2 = bs + ((y + 2) * 8 + x) * 4 + wo;
            union { h8 v; h4 h[2]; } a1v, a2v;
            a1v.h[0] = *(const h4*)&LDSH[ab1];
            a1v.h[1] = *(const h4*)&LDSH[ab1 + 4];
            a2v.h[0] = *(const h4*)&LDSH[ab2];
            a2v.h[1] = *(const h4*)&LDSH[ab2 + 4];
            f32x4 c = MFMA16(a1v.v, w1r0, ZERO4);
            c = MFMA16(a2v.v, w1r1, c);
            #pragma unroll
            for (int r = 0; r < 4; r++)
                A1g[(q * 4 + r) * A1S + p * 16 + col] =
                    f2h(fmaxf(c[r] + b1v, 0.f));
        }
    }
    __syncthreads();

    // ---- 3. stage g1 from registers (no HBM latency here) ----
    {
        int ss = tid / 27, r27 = tid - ss * 27, f0 = r27 * 4;
        #pragma unroll
        for (int j = 0; j < 4; j++) {
            int f = f0 + j, ch = f / 36, p = f - ch * 36;
            LDSH[RA_OFF + ss * BDS4 + ((p / 6 + 1) * 8 + (p % 6) + 1) * 4 + ch] =
                f2h(v1a[j]);
        }
        if (tid < 176) {
            int e4 = tid + 256;
            int ss2 = e4 / 27, r2 = e4 - ss2 * 27, f02 = r2 * 4;
            #pragma unroll
            for (int j = 0; j < 4; j++) {
                int f = f02 + j, ch = f / 36, p = f - ch * 36;
                LDSH[RA_OFF + ss2 * BDS4 + ((p / 6 + 1) * 8 + (p % 6) + 1) * 4 + ch] =
                    f2h(v1b[j]);
            }
        }
    }
    __syncthreads();

    // ---- 4. conv1 g1 ----
    {
        unsigned short* A1g = LDSH + 9856;
        const int bs = RA_OFF + col * BDS4;
        const int rsel = q >> 1, wo = (q & 1) * 8;
        for (int p = wid * 9; p < wid * 9 + 9; p++) {
            int y = p / 6, x = p % 6;
            int ab1 = bs + ((y + rsel) * 8 + x) * 4 + wo;
            int ab2 = bs + ((y + 2) * 8 + x) * 4 + wo;
            union { h8 v; h4 h[2]; } a1v, a2v;
            a1v.h[0] = *(const h4*)&LDSH[ab1];
            a1v.h[1] = *(const h4*)&LDSH[ab1 + 4];
            a2v.h[0] = *(const h4*)&LDSH[ab2];
            a2v.h[1] = *(const h4*)&LDSH[ab2 + 4];
            f32x4 c = MFMA16(a1v.v, w1r0, ZERO4);
            c = MFMA16(a2v.v, w1r1, c);
            #pragma unroll
            for (int r = 0; r < 4; r++)
                A1g[(q * 4 + r) * A1S + p * 16 + col] =
                    f2h(fmaxf(c[r] + b1v, 0.f));
        }
    }
    __syncthreads();

    // ---- 5. conv2: read-once register rows; wave = oc-tile w2, all 36 pos ----
    f32x4 pooled2[9];
    #pragma unroll
    for (int pp = 0; pp < 9; pp++) pooled2[pp] = ZERO4;
    {
        h8 W2r[9];
        #pragma unroll
        for (int t = 0; t < 9; t++)
            W2r[t] = ((const h8*)w2f)[(t * 2 + w2) * 64 + lane];
        float b2v = b2[w2 * 16 + col];
        const int sA1 = col * A1S;
        const int kho = (q & 1) * 8;

        __builtin_amdgcn_s_setprio(1);
        h8 R[3][6];
        #pragma unroll
        for (int x = 0; x < 6; x++) {
            R[0][x] = *(const h8*)&A1[sA1 + (0 * 6 + x) * 16 + kho];
            R[1][x] = *(const h8*)&A1[sA1 + (1 * 6 + x) * 16 + kho];
        }
        #pragma unroll
        for (int y = 0; y < 6; y++) {
            if (y >= 1 && y <= 4) {
                const int nr = y + 1, slot = nr % 3;
                #pragma unroll
                for (int x = 0; x < 6; x++)
                    R[slot][x] = *(const h8*)&A1[sA1 + (nr * 6 + x) * 16 + kho];
            }
            f32x4 acc[6];
            #pragma unroll
            for (int x = 0; x < 6; x++) acc[x] = ZERO4;
            #pragma unroll
            for (int dy = -1; dy <= 1; dy++) {
                const int ry = y + dy;
                if (ry < 0 || ry > 5) continue;
                const int slot = ry % 3;
                #pragma unroll
                for (int x = 0; x < 6; x++)
                    #pragma unroll
                    for (int dx = -1; dx <= 1; dx++) {
                        const int sx = x + dx;
                        if (sx < 0 || sx > 5) continue;
                        acc[x] = MFMA16(R[slot][sx],
                                        W2r[(dy + 1) * 3 + (dx + 1)], acc[x]);
                    }
            }
            const int pr = y >> 1;
            #pragma unroll
            for (int px = 0; px < 3; px++)
                #pragma unroll
                for (int xx = 0; xx < 2; xx++)
                    #pragma unroll
                    for (int r = 0; r < 4; r++)
                        pooled2[pr * 3 + px][r] =
                            fmaxf(pooled2[pr * 3 + px][r],
                                  acc[px * 2 + xx][r] + b2v);
        }
        __builtin_amdgcn_s_setprio(0);
    }
    __syncthreads();   // all A1 reads (block-wide) done before A2 overlays
    #pragma unroll
    for (int pp = 0; pp < 9; pp++)
        #pragma unroll
        for (int r = 0; r < 4; r++)
            A2[(q * 4 + r) * A2S + pp * 32 + w2 * 16 + col] =
                f2h(pooled2[pp][r]);
    __syncthreads();

    // ---- 6. conv3 -> registers (otp = w2) ----
    f32x4 c3a[9], c3b[9];
    {
        const int otp = w2;
        const int sA2 = col * A2S;
        h8 W3r[18];
        #pragma unroll
        for (int f = 0; f < 18; f++)
            W3r[f] = ((const h8*)w3f)[(otp * 18 + f) * 64 + lane];
        __builtin_amdgcn_s_setprio(1);
        #pragma unroll
        for (int p = 0; p < 9; p++) {
            const int y = p / 3, x = p % 3;
            f32x4 acc0 = ZERO4, acc1 = ZERO4;
            #pragma unroll
            for (int t = 0; t < 9; t++) {
                const int sy = y + t / 3 - 1, sx = x + t % 3 - 1;
                if (sy < 0 || sy >= 3 || sx < 0 || sx >= 3) continue;
                h8 a = *(const h8*)&A2[sA2 + (sy * 3 + sx) * 32 + q * 8];
                acc0 = MFMA16(a, W3r[t * 2 + 0], acc0);
                acc1 = MFMA16(a, W3r[t * 2 + 1], acc1);
            }
            c3a[p] = acc0; c3b[p] = acc1;
        }
        __builtin_amdgcn_s_setprio(0);
    }
    __syncthreads();   // all A2 reads done before FT overlays region

    // ---- 7. write FT [p][oc] + quantum + zero tail cols 584..615 ----
    {
        const int otp = w2;
        float b3v0 = b3[(otp * 2 + 0) * 16 + col];
        float b3v1 = b3[(otp * 2 + 1) * 16 + col];
        int oc0 = (otp * 2 + 0) * 16 + col, oc1 = (otp * 2 + 1) * 16 + col;
        #pragma unroll
        for (int p = 0; p < 9; p++)
            #pragma unroll
            for (int r = 0; r < 4; r++) {
                int row = g * 16 + q * 4 + r;
                LDSH[row * FTS + p * 64 + oc0] = f2h(fmaxf(c3a[p][r] + b3v0, 0.f));
                LDSH[row * FTS + p * 64 + oc1] = f2h(fmaxf(c3b[p][r] + b3v1, 0.f));
            }
        if (tid < 128) {
            int ss = tid >> 3, qq = tid & 7;
            LDSH[ss * FTS + 576 + qq] = f2h(qv0);
            LDSH[(ss + 16) * FTS + 576 + qq] = f2h(qv1);
        }
        for (int e = tid; e < 1024; e += 256)
            LDSH[(e >> 5) * FTS + 584 + (e & 31)] = 0;
    }
    __syncthreads();

    // ---- 8. heads L1: K=608 (19 kk), wave does nt-tiles wid*3..+2, both mt ----
    {
        f32x4 acc[2][3];
        #pragma unroll
        for (int mt = 0; mt < 2; mt++)
            #pragma unroll
            for (int nt = 0; nt < 3; nt++) acc[mt][nt] = ZERO4;
        const h8* wp1 = (const h8*)w1hd;
        const int ntb = wid * 3;
        __builtin_amdgcn_s_setprio(1);
        for (int kk = 0; kk < 19; kk++) {
            h8 a0 = *(const h8*)&LDSH[col * FTS + kk * 32 + q * 8];
            h8 a1 = *(const h8*)&LDSH[(16 + col) * FTS + kk * 32 + q * 8];
            h8 b[3];
            #pragma unroll
            for (int nt = 0; nt < 3; nt++)
                b[nt] = wp1[(kk * 12 + ntb + nt) * 64 + lane];
            #pragma unroll
            for (int nt = 0; nt < 3; nt++) {
                acc[0][nt] = MFMA16(a0, b[nt], acc[0][nt]);
                acc[1][nt] = MFMA16(a1, b[nt], acc[1][nt]);
            }
        }
        __builtin_amdgcn_s_setprio(0);
        #pragma unroll
        for (int nt = 0; nt < 3; nt++) {
            int ntg = ntb + nt;
            float bv = (ntg < 8) ? ptb1[ntg * 16 + col] : cfb1[(ntg - 8) * 16 + col];
            #pragma unroll
            for (int mt = 0; mt < 2; mt++)
                #pragma unroll
                for (int r = 0; r < 4; r++)
                    Hb[(mt * 16 + q * 4 + r) * HSH + ntg * 16 + col] =
                        f2h(fmaxf(acc[mt][nt][r] + bv, 0.f));
        }
    }
    __syncthreads();

    // ---- 9. heads L2: nt = wid, both mt; output -> dead FT region (base 0,
    //      stride HSH) so Hb is never overwritten: no pre-write barrier ----
    {
        f32x4 acc2[2];
        acc2[0] = ZERO4; acc2[1] = ZERO4;
        const h8* wp2 = (const h8*)w2hd;
        const int nt2 = wid;
        #pragma unroll
        for (int kk = 0; kk < 4; kk++) {
            h8 a0 = *(const h8*)&Hb[col * HSH + kk * 32 + q * 8];
            h8 a1 = *(const h8*)&Hb[(16 + col) * HSH + kk * 32 + q * 8];
            h8 b = wp2[(kk * 4 + nt2) * 64 + lane];
            acc2[0] = MFMA16(a0, b, acc2[0]);
            acc2[1] = MFMA16(a1, b, acc2[1]);
        }
        float bv2 = ptb2[nt2 * 16 + col];
        #pragma unroll
        for (int mt = 0; mt < 2; mt++)
            #pragma unroll
            for (int r = 0; r < 4; r++)
                LDSH[(mt * 16 + q * 4 + r) * HSH + nt2 * 16 + col] =
                    f2h(fmaxf(acc2[mt][r] + bv2, 0.f));
    }
    __syncthreads();

    // ---- 10. heads L3 + epilogue: waves 0,1 handle mt = wid ----
    if (wid < 2) {
        const int mt = wid;
        f32x4 a3 = ZERO4;
        #pragma unroll
        for (int kk = 0; kk < 4; kk++) {
            // kk 0,1: pt-L2 output (FT region); kk 2,3: cf-L1 output (Hb)
            h8 a = (kk < 2)
                ? *(const h8*)&LDSH[(mt * 16 + col) * HSH + kk * 32 + q * 8]
                : *(const h8*)&Hb[(mt * 16 + col) * HSH + kk * 32 + 64 + q * 8];
            h8 b = ((const h8*)w3hd)[kk * 64 + lane];
            a3 = MFMA16(a, b, a3);
        }
        if (col < 3) {
            float bv = (col < 2) ? ptb3[col] : cfb2[0];
            #pragma unroll
            for (int r = 0; r < 4; r++)
                O[(mt * 16 + q * 4 + r) * 4 + col] = a3[r] + bv;
        }
        if (lane < 16) {
            int s = mt * 16 + lane;
            float l0 = O[s * 4 + 0], l1 = O[s * 4 + 1], l2 = O[s * 4 + 2];
            float m = fmaxf(l0, l1);
            float e0 = expf(l0 - m), e1 = expf(l1 - m);
            float inv = 1.f / (e0 + e1);
            float* op = out + (gg0 + s) * 3;
            op[0] = e0 * inv;
            op[1] = e1 * inv;
            op[2] = 1.f / (1.f + expf(-l2));
        }
    }
}

extern "C" void kernel_launch(void* const* d_in, const int* in_sizes, int n_in,
                              void* d_out, int out_size, void* d_ws, size_t ws_size,
                              hipStream_t stream) {
    const float* board = (const float*)d_in[0];
    const float* c1w  = (const float*)d_in[2];
    const float* c1b  = (const float*)d_in[3];
    const float* c2w  = (const float*)d_in[4];
    const float* c2b  = (const float*)d_in[5];
    const float* c3w  = (const float*)d_in[6];
    const float* c3b  = (const float*)d_in[7];
    const float* qp   = (const float*)d_in[8];
    const float* ptw1 = (const float*)d_in[9];
    const float* ptb1 = (const float*)d_in[10];
    const float* ptw2 = (const float*)d_in[11];
    const float* ptb2 = (const float*)d_in[12];
    const float* ptw3 = (const float*)d_in[13];
    const float* ptb3 = (const float*)d_in[14];
    const float* cfw1 = (const float*)d_in[15];
    const float* cfb1 = (const float*)d_in[16];
    const float* cfw2 = (const float*)d_in[17];
    const float* cfb2 = (const float*)d_in[18];
    float* out = (float*)d_out;

    int Btot = in_sizes[0] / 108;          // 65536

    unsigned short* w1f   = (unsigned short*)d_ws;
    unsigned short* w2f   = (unsigned short*)((char*)d_ws + 2048);
    unsigned short* w3f   = (unsigned short*)((char*)d_ws + 20480);
    unsigned short* w1hd  = (unsigned short*)((char*)d_ws + 57344);
    unsigned short* w2hd  = (unsigned short*)((char*)d_ws + 290816);
    unsigned short* w3hd  = (unsigned short*)((char*)d_ws + 307200);

    hipLaunchKernelGGL(k_prep, dim3(256), dim3(256), 0, stream,
                       c1w, c2w, c3w, ptw1, cfw1, ptw2, ptw3, cfw2,
                       w1f, w2f, w3f, w1hd, w2hd, w3hd);
    hipLaunchKernelGGL(k_fused, dim3(Btot / 32), dim3(256), 0, stream,
                       board, c1b, c2b, c3b, qp, w1f, w2f, w3f,
                       w1hd, w2hd, w3hd, ptb1, ptb2, ptb3, cfb1, cfb2, out);
}

// Round 12
// 167.401 us; speedup vs baseline: 1.1739x; 1.0278x over previous
//
#include <hip/hip_runtime.h>

typedef _Float16 h8 __attribute__((ext_vector_type(8)));
typedef _Float16 h4 __attribute__((ext_vector_type(4)));
typedef float f32x4 __attribute__((ext_vector_type(4)));

union HU { _Float16 h; unsigned short u; };
__device__ __forceinline__ unsigned short f2h(float f) { HU x; x.h = (_Float16)f; return x.u; }
__device__ __forceinline__ float h2f(unsigned short u) { HU x; x.u = u; return (float)x.h; }

#define MFMA16(a, b, c) __builtin_amdgcn_mfma_f32_16x16x32_f16((a), (b), (c), 0, 0, 0)

// ---------------------------------------------------------------------------
// k_prep: r19 packing EXCEPT w2f now packs dx-tap PAIRS for full-K conv2:
//   frag fi (0..8) x w2tile: fi = ptype*3 + krow
//     ptype0 "pair01": k<16 -> tap (krow, dx=-1), k>=16 -> (krow, dx=0)
//     ptype1 "pair12": k<16 -> tap (krow, dx=0),  k>=16 -> (krow, dx=+1)
//     ptype2 "solo2" : k<16 -> tap (krow, dx=+1), k>=16 -> zero
//   (A-operand spans positions p,p+1 contiguously in A1's [pos][16ic] layout)
// ---------------------------------------------------------------------------
__global__ void k_prep(const float* __restrict__ w1, const float* __restrict__ w2,
                       const float* __restrict__ w3,
                       const float* __restrict__ ptw1, const float* __restrict__ cfw1,
                       const float* __restrict__ ptw2, const float* __restrict__ ptw3,
                       const float* __restrict__ cfw2,
                       unsigned short* __restrict__ w1f,
                       unsigned short* __restrict__ w2f,
                       unsigned short* __restrict__ w3f,
                       unsigned short* __restrict__ w1hd,
                       unsigned short* __restrict__ w2hd,
                       unsigned short* __restrict__ w3hd) {
    int gid = blockIdx.x * 256 + threadIdx.x;
    int gs = gridDim.x * 256;
    for (int e = gid; e < 1024; e += gs) {
        int f = e >> 9, lane = (e >> 3) & 63, j = e & 7;
        int k = ((lane >> 4) << 3) + j, oc = lane & 15;
        int r, within;
        if (f == 0) { r = k >> 4; within = k & 15; }
        else        { r = 2;      within = k; }
        int tx = within >> 2, ch = within & 3;
        float v = 0.f;
        if (tx < 3 && ch < 3) v = w1[oc * 27 + ch * 9 + r * 3 + tx];
        w1f[e] = f2h(v);
    }
    for (int e = gid; e < 9216; e += gs) {
        int j = e & 7, lane = (e >> 3) & 63, fo = e >> 9;   // fo = fi*2 + w2t
        int w2t = fo & 1, fi = fo >> 1;                      // fi 0..8
        int k = ((lane >> 4) * 8) + j, oc = w2t * 16 + (lane & 15);
        int kic = k & 15, khi = k >> 4;
        int ptype = fi / 3, krow = fi % 3;
        int t = -1;
        if (ptype == 0) t = krow * 3 + khi;                  // dx=-1,0
        else if (ptype == 1) t = krow * 3 + 1 + khi;         // dx=0,+1
        else if (khi == 0) t = krow * 3 + 2;                 // dx=+1 solo
        float v = (t >= 0) ? w2[oc * 144 + kic * 9 + t] : 0.f;
        w2f[e] = f2h(v);
    }
    for (int e = gid; e < 18432; e += gs) {
        int j = e & 7, lane = (e >> 3) & 63, fo = e >> 9;   // fo = (otp*9+t)*2+oti
        int oti = fo & 1, t = (fo >> 1) % 9, otp = (fo >> 1) / 9;
        int ic = ((lane >> 4) * 8) + j, oc = (otp * 2 + oti) * 16 + (lane & 15);
        w3f[e] = f2h(w3[oc * 288 + ic * 9 + t]);
    }
    for (int s = gid; s < 608 * 192; s += gs) {
        int k = s / 192, n = s - k * 192;
        float v = 0.f;
        if (k < 584) {
            int f = (k < 576) ? ((k & 63) * 9 + (k >> 6)) : k;
            v = (n < 128) ? ptw1[f * 128 + n] : cfw1[f * 64 + (n - 128)];
        }
        int kk = k >> 5, hi = (k & 31) >> 3, j = k & 7, nt = n >> 4;
        int e = (((kk * 12 + nt) << 6) | (hi << 4) | (n & 15)) << 3 | j;
        w1hd[e] = f2h(v);
    }
    for (int s = gid; s < 8192; s += gs) {
        int k = s >> 6, n = s & 63;
        float v = ptw2[k * 64 + n];
        int kk = k >> 5, hi = (k & 31) >> 3, j = k & 7, nt = n >> 4;
        int e = ((((kk << 2) | nt) << 6) | (hi << 4) | (n & 15)) << 3 | j;
        w2hd[e] = f2h(v);
    }
    for (int e = gid; e < 2048; e += gs) {
        int j = e & 7, lane = (e >> 3) & 63, kk = e >> 9;
        int k = kk * 32 + ((lane >> 4) * 8) + j, n = lane & 15;
        float v = 0.f;
        if (k < 64) { if (n < 2) v = ptw3[k * 2 + n]; }
        else        { if (n == 2) v = cfw2[k - 64]; }
        w3hd[e] = f2h(v);
    }
}

// ---------------------------------------------------------------------------
// k_fused, round 24: r19 (82.5 us best) with conv2 on FULL-K paired-tap
// MFMAs: B packs two dx taps per K=32 (A spans positions p,p+1 contiguously),
// so per output-x/kernel-row: interior 2 MFMA (was 3), x=0 and x=5 edges
// 1 MFMA (was 2). conv2 256 -> 160 MFMA/wave (-37.5%), block 2056 -> 1672
// MFMA16-equiv (-19%). A-read addresses identical (kho = q*8 now spans the
// pair); out-of-range tail reads hit zero weights and stay in-allocation.
// Register profile unchanged (9 h8 B-frags, acc[6]).
// ---------------------------------------------------------------------------
#define BDS4 260
#define A1S 584
#define A2S 296
#define FTS 616
#define HSH 200
#define RA_OFF 19712
#define O_OFF 26112
#define LDSTOT 26368

__global__ __launch_bounds__(256, 3) void k_fused(
    const float* __restrict__ board,
    const float* __restrict__ b1, const float* __restrict__ b2,
    const float* __restrict__ b3, const float* __restrict__ qp,
    const unsigned short* __restrict__ w1f,
    const unsigned short* __restrict__ w2f,
    const unsigned short* __restrict__ w3f,
    const unsigned short* __restrict__ w1hd,
    const unsigned short* __restrict__ w2hd,
    const unsigned short* __restrict__ w3hd,
    const float* __restrict__ ptb1, const float* __restrict__ ptb2,
    const float* __restrict__ ptb3, const float* __restrict__ cfb1,
    const float* __restrict__ cfb2,
    float* __restrict__ out)
{
    __shared__ __align__(16) unsigned short LDSH[LDSTOT];
    const int tid = threadIdx.x, wid = tid >> 6, lane = tid & 63;
    const int g = wid >> 1, w2 = wid & 1;
    const int col = lane & 15, q = lane >> 4;
    const long long gg0 = (long long)blockIdx.x * 32;
    const f32x4 ZERO4 = {0.f, 0.f, 0.f, 0.f};

    unsigned short* A1 = LDSH + g * 9856;
    unsigned short* A2 = A1;                          // overlay (barriered)
    unsigned short* Hb = LDSH + RA_OFF;               // overlays BD (dead)
    float* O = (float*)(LDSH + O_OFF);

    // ---- 0. issue board preloads (both groups) + quantum global loads ----
    const f32x4* bp4 = (const f32x4*)(board + gg0 * 108);
    f32x4 v0a = bp4[tid];                 // g0
    f32x4 v0b = ZERO4, v1b = ZERO4;
    if (tid < 176) v0b = bp4[tid + 256];
    f32x4 v1a = bp4[tid + 432];           // g1
    if (tid < 176) v1b = bp4[tid + 688];

    float xq0 = 0.f, xn0 = 0.f, xq1 = 0.f, xn1 = 0.f;
    if (tid < 128) {
        int ss = tid >> 3, qq = tid & 7, e2 = (qq + 1) & 7;
        const float* b0p = board + (gg0 + ss) * 108;
        xq0 = b0p[qq];  xn0 = b0p[e2];
        xq1 = b0p[16 * 108 + qq];  xn1 = b0p[16 * 108 + e2];
    }

    // ---- 1. stage g0 + zero halo/ch3/spare (disjoint writes, one phase) ----
    {
        if (tid < 128) {
            int ss = tid >> 3, row = tid & 7;
            unsigned long long* Z =
                (unsigned long long*)&LDSH[RA_OFF + ss * BDS4];
            if (row == 0) {
                #pragma unroll
                for (int i = 0; i < 8; i++) Z[i] = 0ULL;
            } else if (row == 7) {
                #pragma unroll
                for (int i = 56; i < 65; i++) Z[i] = 0ULL;   // row 7 + spares
            } else {
                Z[row * 8] = 0ULL;          // col 0 cell
                Z[row * 8 + 7] = 0ULL;      // col 7 cell
                #pragma unroll
                for (int c = 1; c < 7; c++) // interior ch3
                    LDSH[RA_OFF + ss * BDS4 + row * 32 + c * 4 + 3] = 0;
            }
        }
        int ss = tid / 27, r27 = tid - ss * 27, f0 = r27 * 4;
        #pragma unroll
        for (int j = 0; j < 4; j++) {
            int f = f0 + j, ch = f / 36, p = f - ch * 36;
            LDSH[RA_OFF + ss * BDS4 + ((p / 6 + 1) * 8 + (p % 6) + 1) * 4 + ch] =
                f2h(v0a[j]);
        }
        if (tid < 176) {
            int e4 = tid + 256;
            int ss2 = e4 / 27, r2 = e4 - ss2 * 27, f02 = r2 * 4;
            #pragma unroll
            for (int j = 0; j < 4; j++) {
                int f = f02 + j, ch = f / 36, p = f - ch * 36;
                LDSH[RA_OFF + ss2 * BDS4 + ((p / 6 + 1) * 8 + (p % 6) + 1) * 4 + ch] =
                    f2h(v0b[j]);
            }
        }
    }
    __syncthreads();

    // ---- 2. conv1 g0 (+ quantum chains on waves 0,1 — VALU overlaps MFMA) ----
    float qv0 = 0.f, qv1 = 0.f;
    h8 w1r0 = ((const h8*)w1f)[lane];
    h8 w1r1 = ((const h8*)w1f)[64 + lane];
    float b1v = b1[col];
    if (tid < 128) {
        int qq = tid & 7;
        float s0 = 0.f, s1 = 0.f;
        for (int l = 0; l < 3; l++) {
            float a0 = qp[l * 24 + qq * 3], a1 = qp[l * 24 + qq * 3 + 1],
                  a2 = qp[l * 24 + qq * 3 + 2];
            s0 = sinf(a0 * xq0) * cosf(a1 * xn0) + tanhf(a2 * s0);
            s1 = sinf(a0 * xq1) * cosf(a1 * xn1) + tanhf(a2 * s1);
        }
        qv0 = s0; qv1 = s1;
    }
    {
        unsigned short* A1g = LDSH;
        const int bs = RA_OFF + col * BDS4;
        const int rsel = q >> 1, wo = (q & 1) * 8;
        for (int p = wid * 9; p < wid * 9 + 9; p++) {
            int y = p / 6, x = p % 6;
            int ab1 = bs + ((y + rsel) * 8 + x) * 4 + wo;
            int ab2 = bs + ((y + 2) * 8 + x) * 4 + wo;
            union { h8 v; h4 h[2]; } a1v, a2v;
            a1v.h[0] = *(const h4*)&LDSH[ab1];
            a1v.h[1] = *(const h4*)&LDSH[ab1 + 4];
            a2v.h[0] = *(const h4*)&LDSH[ab2];
            a2v.h[1] = *(const h4*)&LDSH[ab2 + 4];
            f32x4 c = MFMA16(a1v.v, w1r0, ZERO4);
            c = MFMA16(a2v.v, w1r1, c);
            #pragma unroll
            for (int r = 0; r < 4; r++)
                A1g[(q * 4 + r) * A1S + p * 16 + col] =
                    f2h(fmaxf(c[r] + b1v, 0.f));
        }
    }
    __syncthreads();

    // ---- 3. stage g1 from registers (no HBM latency here) ----
    {
        int ss = tid / 27, r27 = tid - ss * 27, f0 = r27 * 4;
        #pragma unroll
        for (int j = 0; j < 4; j++) {
            int f = f0 + j, ch = f / 36, p = f - ch * 36;
            LDSH[RA_OFF + ss * BDS4 + ((p / 6 + 1) * 8 + (p % 6) + 1) * 4 + ch] =
                f2h(v1a[j]);
        }
        if (tid < 176) {
            int e4 = tid + 256;
            int ss2 = e4 / 27, r2 = e4 - ss2 * 27, f02 = r2 * 4;
            #pragma unroll
            for (int j = 0; j < 4; j++) {
                int f = f02 + j, ch = f / 36, p = f - ch * 36;
                LDSH[RA_OFF + ss2 * BDS4 + ((p / 6 + 1) * 8 + (p % 6) + 1) * 4 + ch] =
                    f2h(v1b[j]);
            }
        }
    }
    __syncthreads();

    // ---- 4. conv1 g1 ----
    {
        unsigned short* A1g = LDSH + 9856;
        const int bs = RA_OFF + col * BDS4;
        const int rsel = q >> 1, wo = (q & 1) * 8;
        for (int p = wid * 9; p < wid * 9 + 9; p++) {
            int y = p / 6, x = p % 6;
            int ab1 = bs + ((y + rsel) * 8 + x) * 4 + wo;
            int ab2 = bs + ((y + 2) * 8 + x) * 4 + wo;
            union { h8 v; h4 h[2]; } a1v, a2v;
            a1v.h[0] = *(const h4*)&LDSH[ab1];
            a1v.h[1] = *(const h4*)&LDSH[ab1 + 4];
            a2v.h[0] = *(const h4*)&LDSH[ab2];
            a2v.h[1] = *(const h4*)&LDSH[ab2 + 4];
            f32x4 c = MFMA16(a1v.v, w1r0, ZERO4);
            c = MFMA16(a2v.v, w1r1, c);
            #pragma unroll
            for (int r = 0; r < 4; r++)
                A1g[(q * 4 + r) * A1S + p * 16 + col] =
                    f2h(fmaxf(c[r] + b1v, 0.f));
        }
    }
    __syncthreads();

    // ---- 5. conv2: full-K paired-tap MFMAs. A-frag = 32 halfs spanning
    //      positions (p, p+1); q*8 selects the k-group. Per dy-row:
    //      x=0 pair12, x=1..4 pair01+solo2, x=5 pair01 -> 10 MFMA (was 16).
    f32x4 pooled2[9];
    #pragma unroll
    for (int pp = 0; pp < 9; pp++) pooled2[pp] = ZERO4;
    {
        h8 Wp01[3], Wp12[3], Ws2[3];
        #pragma unroll
        for (int d = 0; d < 3; d++) {
            Wp01[d] = ((const h8*)w2f)[((0 + d) * 2 + w2) * 64 + lane];
            Wp12[d] = ((const h8*)w2f)[((3 + d) * 2 + w2) * 64 + lane];
            Ws2[d]  = ((const h8*)w2f)[((6 + d) * 2 + w2) * 64 + lane];
        }
        float b2v = b2[w2 * 16 + col];
        const int sA1 = col * A1S;
        const int kho = q * 8;           // full K=32 across position pair

        __builtin_amdgcn_s_setprio(1);
        h8 R[3][6];
        #pragma unroll
        for (int x = 0; x < 6; x++) {
            R[0][x] = *(const h8*)&A1[sA1 + (0 * 6 + x) * 16 + kho];
            R[1][x] = *(const h8*)&A1[sA1 + (1 * 6 + x) * 16 + kho];
        }
        #pragma unroll
        for (int y = 0; y < 6; y++) {
            if (y >= 1 && y <= 4) {
                const int nr = y + 1, slot = nr % 3;
                #pragma unroll
                for (int x = 0; x < 6; x++)
                    R[slot][x] = *(const h8*)&A1[sA1 + (nr * 6 + x) * 16 + kho];
            }
            f32x4 acc[6];
            #pragma unroll
            for (int x = 0; x < 6; x++) acc[x] = ZERO4;
            #pragma unroll
            for (int dy = -1; dy <= 1; dy++) {
                const int ry = y + dy;
                if (ry < 0 || ry > 5) continue;
                const int slot = ry % 3, di = dy + 1;
                acc[0] = MFMA16(R[slot][0], Wp12[di], acc[0]);
                #pragma unroll
                for (int x = 1; x < 5; x++) {
                    acc[x] = MFMA16(R[slot][x - 1], Wp01[di], acc[x]);
                    acc[x] = MFMA16(R[slot][x + 1], Ws2[di], acc[x]);
                }
                acc[5] = MFMA16(R[slot][4], Wp01[di], acc[5]);
            }
            const int pr = y >> 1;
            #pragma unroll
            for (int px = 0; px < 3; px++)
                #pragma unroll
                for (int xx = 0; xx < 2; xx++)
                    #pragma unroll
                    for (int r = 0; r < 4; r++)
                        pooled2[pr * 3 + px][r] =
                            fmaxf(pooled2[pr * 3 + px][r],
                                  acc[px * 2 + xx][r] + b2v);
        }
        __builtin_amdgcn_s_setprio(0);
    }
    __syncthreads();   // all A1 reads (block-wide) done before A2 overlays
    #pragma unroll
    for (int pp = 0; pp < 9; pp++)
        #pragma unroll
        for (int r = 0; r < 4; r++)
            A2[(q * 4 + r) * A2S + pp * 32 + w2 * 16 + col] =
                f2h(pooled2[pp][r]);
    __syncthreads();

    // ---- 6. conv3 -> registers (otp = w2) ----
    f32x4 c3a[9], c3b[9];
    {
        const int otp = w2;
        const int sA2 = col * A2S;
        h8 W3r[18];
        #pragma unroll
        for (int f = 0; f < 18; f++)
            W3r[f] = ((const h8*)w3f)[(otp * 18 + f) * 64 + lane];
        __builtin_amdgcn_s_setprio(1);
        #pragma unroll
        for (int p = 0; p < 9; p++) {
            const int y = p / 3, x = p % 3;
            f32x4 acc0 = ZERO4, acc1 = ZERO4;
            #pragma unroll
            for (int t = 0; t < 9; t++) {
                const int sy = y + t / 3 - 1, sx = x + t % 3 - 1;
                if (sy < 0 || sy >= 3 || sx < 0 || sx >= 3) continue;
                h8 a = *(const h8*)&A2[sA2 + (sy * 3 + sx) * 32 + q * 8];
                acc0 = MFMA16(a, W3r[t * 2 + 0], acc0);
                acc1 = MFMA16(a, W3r[t * 2 + 1], acc1);
            }
            c3a[p] = acc0; c3b[p] = acc1;
        }
        __builtin_amdgcn_s_setprio(0);
    }
    __syncthreads();   // all A2 reads done before FT overlays region

    // ---- 7. write FT [p][oc] + quantum + zero tail cols 584..615 ----
    {
        const int otp = w2;
        float b3v0 = b3[(otp * 2 + 0) * 16 + col];
        float b3v1 = b3[(otp * 2 + 1) * 16 + col];
        int oc0 = (otp * 2 + 0) * 16 + col, oc1 = (otp * 2 + 1) * 16 + col;
        #pragma unroll
        for (int p = 0; p < 9; p++)
            #pragma unroll
            for (int r = 0; r < 4; r++) {
                int row = g * 16 + q * 4 + r;
                LDSH[row * FTS + p * 64 + oc0] = f2h(fmaxf(c3a[p][r] + b3v0, 0.f));
                LDSH[row * FTS + p * 64 + oc1] = f2h(fmaxf(c3b[p][r] + b3v1, 0.f));
            }
        if (tid < 128) {
            int ss = tid >> 3, qq = tid & 7;
            LDSH[ss * FTS + 576 + qq] = f2h(qv0);
            LDSH[(ss + 16) * FTS + 576 + qq] = f2h(qv1);
        }
        for (int e = tid; e < 1024; e += 256)
            LDSH[(e >> 5) * FTS + 584 + (e & 31)] = 0;
    }
    __syncthreads();

    // ---- 8. heads L1: K=608 (19 kk), wave does nt-tiles wid*3..+2, both mt ----
    {
        f32x4 acc[2][3];
        #pragma unroll
        for (int mt = 0; mt < 2; mt++)
            #pragma unroll
            for (int nt = 0; nt < 3; nt++) acc[mt][nt] = ZERO4;
        const h8* wp1 = (const h8*)w1hd;
        const int ntb = wid * 3;
        __builtin_amdgcn_s_setprio(1);
        for (int kk = 0; kk < 19; kk++) {
            h8 a0 = *(const h8*)&LDSH[col * FTS + kk * 32 + q * 8];
            h8 a1 = *(const h8*)&LDSH[(16 + col) * FTS + kk * 32 + q * 8];
            h8 b[3];
            #pragma unroll
            for (int nt = 0; nt < 3; nt++)
                b[nt] = wp1[(kk * 12 + ntb + nt) * 64 + lane];
            #pragma unroll
            for (int nt = 0; nt < 3; nt++) {
                acc[0][nt] = MFMA16(a0, b[nt], acc[0][nt]);
                acc[1][nt] = MFMA16(a1, b[nt], acc[1][nt]);
            }
        }
        __builtin_amdgcn_s_setprio(0);
        #pragma unroll
        for (int nt = 0; nt < 3; nt++) {
            int ntg = ntb + nt;
            float bv = (ntg < 8) ? ptb1[ntg * 16 + col] : cfb1[(ntg - 8) * 16 + col];
            #pragma unroll
            for (int mt = 0; mt < 2; mt++)
                #pragma unroll
                for (int r = 0; r < 4; r++)
                    Hb[(mt * 16 + q * 4 + r) * HSH + ntg * 16 + col] =
                        f2h(fmaxf(acc[mt][nt][r] + bv, 0.f));
        }
    }
    __syncthreads();

    // ---- 9. heads L2: nt = wid, both mt; output -> dead FT region (base 0,
    //      stride HSH) so Hb is never overwritten: no pre-write barrier ----
    {
        f32x4 acc2[2];
        acc2[0] = ZERO4; acc2[1] = ZERO4;
        const h8* wp2 = (const h8*)w2hd;
        const int nt2 = wid;
        #pragma unroll
        for (int kk = 0; kk < 4; kk++) {
            h8 a0 = *(const h8*)&Hb[col * HSH + kk * 32 + q * 8];
            h8 a1 = *(const h8*)&Hb[(16 + col) * HSH + kk * 32 + q * 8];
            h8 b = wp2[(kk * 4 + nt2) * 64 + lane];
            acc2[0] = MFMA16(a0, b, acc2[0]);
            acc2[1] = MFMA16(a1, b, acc2[1]);
        }
        float bv2 = ptb2[nt2 * 16 + col];
        #pragma unroll
        for (int mt = 0; mt < 2; mt++)
            #pragma unroll
            for (int r = 0; r < 4; r++)
                LDSH[(mt * 16 + q * 4 + r) * HSH + nt2 * 16 + col] =
                    f2h(fmaxf(acc2[mt][r] + bv2, 0.f));
    }
    __syncthreads();

    // ---- 10. heads L3 + epilogue: waves 0,1 handle mt = wid ----
    if (wid < 2) {
        const int mt = wid;
        f32x4 a3 = ZERO4;
        #pragma unroll
        for (int kk = 0; kk < 4; kk++) {
            // kk 0,1: pt-L2 output (FT region); kk 2,3: cf-L1 output (Hb)
            h8 a = (kk < 2)
                ? *(const h8*)&LDSH[(mt * 16 + col) * HSH + kk * 32 + q * 8]
                : *(const h8*)&Hb[(mt * 16 + col) * HSH + kk * 32 + 64 + q * 8];
            h8 b = ((const h8*)w3hd)[kk * 64 + lane];
            a3 = MFMA16(a, b, a3);
        }
        if (col < 3) {
            float bv = (col < 2) ? ptb3[col] : cfb2[0];
            #pragma unroll
            for (int r = 0; r < 4; r++)
                O[(mt * 16 + q * 4 + r) * 4 + col] = a3[r] + bv;
        }
        if (lane < 16) {
            int s = mt * 16 + lane;
            float l0 = O[s * 4 + 0], l1 = O[s * 4 + 1], l2 = O[s * 4 + 2];
            float m = fmaxf(l0, l1);
            float e0 = expf(l0 - m), e1 = expf(l1 - m);
            float inv = 1.f / (e0 + e1);
            float* op = out + (gg0 + s) * 3;
            op[0] = e0 * inv;
            op[1] = e1 * inv;
            op[2] = 1.f / (1.f + expf(-l2));
        }
    }
}

extern "C" void kernel_launch(void* const* d_in, const int* in_sizes, int n_in,
                              void* d_out, int out_size, void* d_ws, size_t ws_size,
                              hipStream_t stream) {
    const float* board = (const float*)d_in[0];
    const float* c1w  = (const float*)d_in[2];
    const float* c1b  = (const float*)d_in[3];
    const float* c2w  = (const float*)d_in[4];
    const float* c2b  = (const float*)d_in[5];
    const float* c3w  = (const float*)d_in[6];
    const float* c3b  = (const float*)d_in[7];
    const float* qp   = (const float*)d_in[8];
    const float* ptw1 = (const float*)d_in[9];
    const float* ptb1 = (const float*)d_in[10];
    const float* ptw2 = (const float*)d_in[11];
    const float* ptb2 = (const float*)d_in[12];
    const float* ptw3 = (const float*)d_in[13];
    const float* ptb3 = (const float*)d_in[14];
    const float* cfw1 = (const float*)d_in[15];
    const float* cfb1 = (const float*)d_in[16];
    const float* cfw2 = (const float*)d_in[17];
    const float* cfb2 = (const float*)d_in[18];
    float* out = (float*)d_out;

    int Btot = in_sizes[0] / 108;          // 65536

    unsigned short* w1f   = (unsigned short*)d_ws;
    unsigned short* w2f   = (unsigned short*)((char*)d_ws + 2048);
    unsigned short* w3f   = (unsigned short*)((char*)d_ws + 20480);
    unsigned short* w1hd  = (unsigned short*)((char*)d_ws + 57344);
    unsigned short* w2hd  = (unsigned short*)((char*)d_ws + 290816);
    unsigned short* w3hd  = (unsigned short*)((char*)d_ws + 307200);

    hipLaunchKernelGGL(k_prep, dim3(256), dim3(256), 0, stream,
                       c1w, c2w, c3w, ptw1, cfw1, ptw2, ptw3, cfw2,
                       w1f, w2f, w3f, w1hd, w2hd, w3hd);
    hipLaunchKernelGGL(k_fused, dim3(Btot / 32), dim3(256), 0, stream,
                       board, c1b, c2b, c3b, qp, w1f, w2f, w3f,
                       w1hd, w2hd, w3hd, ptb1, ptb2, ptb3, cfb1, cfb2, out);
}

// Round 15
// 165.658 us; speedup vs baseline: 1.1862x; 1.0105x over previous
//
#include <hip/hip_runtime.h>

typedef _Float16 h8 __attribute__((ext_vector_type(8)));
typedef _Float16 h4 __attribute__((ext_vector_type(4)));
typedef float f32x4 __attribute__((ext_vector_type(4)));

union HU { _Float16 h; unsigned short u; };
__device__ __forceinline__ unsigned short f2h(float f) { HU x; x.h = (_Float16)f; return x.u; }
__device__ __forceinline__ float h2f(unsigned short u) { HU x; x.u = u; return (float)x.h; }

#define MFMA16(a, b, c) __builtin_amdgcn_mfma_f32_16x16x32_f16((a), (b), (c), 0, 0, 0)

// ---------------------------------------------------------------------------
// k_prep: byte-identical to round 24 (paired-tap w2f packing).
// ---------------------------------------------------------------------------
__global__ void k_prep(const float* __restrict__ w1, const float* __restrict__ w2,
                       const float* __restrict__ w3,
                       const float* __restrict__ ptw1, const float* __restrict__ cfw1,
                       const float* __restrict__ ptw2, const float* __restrict__ ptw3,
                       const float* __restrict__ cfw2,
                       unsigned short* __restrict__ w1f,
                       unsigned short* __restrict__ w2f,
                       unsigned short* __restrict__ w3f,
                       unsigned short* __restrict__ w1hd,
                       unsigned short* __restrict__ w2hd,
                       unsigned short* __restrict__ w3hd) {
    int gid = blockIdx.x * 256 + threadIdx.x;
    int gs = gridDim.x * 256;
    for (int e = gid; e < 1024; e += gs) {
        int f = e >> 9, lane = (e >> 3) & 63, j = e & 7;
        int k = ((lane >> 4) << 3) + j, oc = lane & 15;
        int r, within;
        if (f == 0) { r = k >> 4; within = k & 15; }
        else        { r = 2;      within = k; }
        int tx = within >> 2, ch = within & 3;
        float v = 0.f;
        if (tx < 3 && ch < 3) v = w1[oc * 27 + ch * 9 + r * 3 + tx];
        w1f[e] = f2h(v);
    }
    for (int e = gid; e < 9216; e += gs) {
        int j = e & 7, lane = (e >> 3) & 63, fo = e >> 9;   // fo = fi*2 + w2t
        int w2t = fo & 1, fi = fo >> 1;                      // fi 0..8
        int k = ((lane >> 4) * 8) + j, oc = w2t * 16 + (lane & 15);
        int kic = k & 15, khi = k >> 4;
        int ptype = fi / 3, krow = fi % 3;
        int t = -1;
        if (ptype == 0) t = krow * 3 + khi;                  // dx=-1,0
        else if (ptype == 1) t = krow * 3 + 1 + khi;         // dx=0,+1
        else if (khi == 0) t = krow * 3 + 2;                 // dx=+1 solo
        float v = (t >= 0) ? w2[oc * 144 + kic * 9 + t] : 0.f;
        w2f[e] = f2h(v);
    }
    for (int e = gid; e < 18432; e += gs) {
        int j = e & 7, lane = (e >> 3) & 63, fo = e >> 9;   // fo = (otp*9+t)*2+oti
        int oti = fo & 1, t = (fo >> 1) % 9, otp = (fo >> 1) / 9;
        int ic = ((lane >> 4) * 8) + j, oc = (otp * 2 + oti) * 16 + (lane & 15);
        w3f[e] = f2h(w3[oc * 288 + ic * 9 + t]);
    }
    for (int s = gid; s < 608 * 192; s += gs) {
        int k = s / 192, n = s - k * 192;
        float v = 0.f;
        if (k < 584) {
            int f = (k < 576) ? ((k & 63) * 9 + (k >> 6)) : k;
            v = (n < 128) ? ptw1[f * 128 + n] : cfw1[f * 64 + (n - 128)];
        }
        int kk = k >> 5, hi = (k & 31) >> 3, j = k & 7, nt = n >> 4;
        int e = (((kk * 12 + nt) << 6) | (hi << 4) | (n & 15)) << 3 | j;
        w1hd[e] = f2h(v);
    }
    for (int s = gid; s < 8192; s += gs) {
        int k = s >> 6, n = s & 63;
        float v = ptw2[k * 64 + n];
        int kk = k >> 5, hi = (k & 31) >> 3, j = k & 7, nt = n >> 4;
        int e = ((((kk << 2) | nt) << 6) | (hi << 4) | (n & 15)) << 3 | j;
        w2hd[e] = f2h(v);
    }
    for (int e = gid; e < 2048; e += gs) {
        int j = e & 7, lane = (e >> 3) & 63, kk = e >> 9;
        int k = kk * 32 + ((lane >> 4) * 8) + j, n = lane & 15;
        float v = 0.f;
        if (k < 64) { if (n < 2) v = ptw3[k * 2 + n]; }
        else        { if (n == 2) v = cfw2[k - 64]; }
        w3hd[e] = f2h(v);
    }
}

// ---------------------------------------------------------------------------
// k_fused, round 27: r26 with the FT tail-zero bug fixed.
// Root cause of r25/r26 failures: the "u64 tail-zero" covered only 16 of 32
// cols (584..615) per row. FT rows 15/31 overlap never-written LDS (group
// halfs [9344,9856)+[19200,19712)), so the unzeroed cols carried startup
// garbage incl. possible fp16 NaN; NaN x 0-weight = NaN in MFMA, then
// relu's fmaxf(NaN,0)=0 silently zeroed head-L1 rows 15/31 -> 1.3-1.8e-2.
// Restored r24's full scalar zero loop. Kept from r25/r26 (numerics-neutral):
// quantum spread over 256 threads (1 precise libm chain each, halves the
// conv1-g0 transcendental tail), setprio on conv1. Else == r24 (78 us).
// ---------------------------------------------------------------------------
#define BDS4 260
#define A1S 584
#define A2S 296
#define FTS 616
#define HSH 200
#define RA_OFF 19712
#define O_OFF 26112
#define LDSTOT 26368

__global__ __launch_bounds__(256, 3) void k_fused(
    const float* __restrict__ board,
    const float* __restrict__ b1, const float* __restrict__ b2,
    const float* __restrict__ b3, const float* __restrict__ qp,
    const unsigned short* __restrict__ w1f,
    const unsigned short* __restrict__ w2f,
    const unsigned short* __restrict__ w3f,
    const unsigned short* __restrict__ w1hd,
    const unsigned short* __restrict__ w2hd,
    const unsigned short* __restrict__ w3hd,
    const float* __restrict__ ptb1, const float* __restrict__ ptb2,
    const float* __restrict__ ptb3, const float* __restrict__ cfb1,
    const float* __restrict__ cfb2,
    float* __restrict__ out)
{
    __shared__ __align__(16) unsigned short LDSH[LDSTOT];
    const int tid = threadIdx.x, wid = tid >> 6, lane = tid & 63;
    const int g = wid >> 1, w2 = wid & 1;
    const int col = lane & 15, q = lane >> 4;
    const long long gg0 = (long long)blockIdx.x * 32;
    const f32x4 ZERO4 = {0.f, 0.f, 0.f, 0.f};

    unsigned short* A1 = LDSH + g * 9856;
    unsigned short* A2 = A1;                          // overlay (barriered)
    unsigned short* Hb = LDSH + RA_OFF;               // overlays BD (dead)
    float* O = (float*)(LDSH + O_OFF);

    // ---- 0. issue board preloads (both groups) + quantum global loads ----
    const f32x4* bp4 = (const f32x4*)(board + gg0 * 108);
    f32x4 v0a = bp4[tid];                 // g0
    f32x4 v0b = ZERO4, v1b = ZERO4;
    if (tid < 176) v0b = bp4[tid + 256];
    f32x4 v1a = bp4[tid + 432];           // g1
    if (tid < 176) v1b = bp4[tid + 688];

    float xq, xn;                         // per-thread quantum inputs
    {
        int gq = tid >> 7, ss = (tid >> 3) & 15, qq = tid & 7, e2 = (qq + 1) & 7;
        const float* b0p = board + (gg0 + gq * 16 + ss) * 108;
        xq = b0p[qq];  xn = b0p[e2];
    }

    // ---- 1. stage g0 + zero halo/ch3/spare (disjoint writes, one phase) ----
    {
        if (tid < 128) {
            int ss = tid >> 3, row = tid & 7;
            unsigned long long* Z =
                (unsigned long long*)&LDSH[RA_OFF + ss * BDS4];
            if (row == 0) {
                #pragma unroll
                for (int i = 0; i < 8; i++) Z[i] = 0ULL;
            } else if (row == 7) {
                #pragma unroll
                for (int i = 56; i < 65; i++) Z[i] = 0ULL;   // row 7 + spares
            } else {
                Z[row * 8] = 0ULL;          // col 0 cell
                Z[row * 8 + 7] = 0ULL;      // col 7 cell
                #pragma unroll
                for (int c = 1; c < 7; c++) // interior ch3
                    LDSH[RA_OFF + ss * BDS4 + row * 32 + c * 4 + 3] = 0;
            }
        }
        int ss = tid / 27, r27 = tid - ss * 27, f0 = r27 * 4;
        #pragma unroll
        for (int j = 0; j < 4; j++) {
            int f = f0 + j, ch = f / 36, p = f - ch * 36;
            LDSH[RA_OFF + ss * BDS4 + ((p / 6 + 1) * 8 + (p % 6) + 1) * 4 + ch] =
                f2h(v0a[j]);
        }
        if (tid < 176) {
            int e4 = tid + 256;
            int ss2 = e4 / 27, r2 = e4 - ss2 * 27, f02 = r2 * 4;
            #pragma unroll
            for (int j = 0; j < 4; j++) {
                int f = f02 + j, ch = f / 36, p = f - ch * 36;
                LDSH[RA_OFF + ss2 * BDS4 + ((p / 6 + 1) * 8 + (p % 6) + 1) * 4 + ch] =
                    f2h(v0b[j]);
            }
        }
    }
    __syncthreads();

    // ---- 2. conv1 g0 + quantum (all 256 threads, precise, 1 chain each) ----
    float qv;
    h8 w1r0 = ((const h8*)w1f)[lane];
    h8 w1r1 = ((const h8*)w1f)[64 + lane];
    float b1v = b1[col];
    {
        int qq = tid & 7;
        float st = 0.f;
        for (int l = 0; l < 3; l++) {
            float a0 = qp[l * 24 + qq * 3], a1 = qp[l * 24 + qq * 3 + 1],
                  a2 = qp[l * 24 + qq * 3 + 2];
            st = sinf(a0 * xq) * cosf(a1 * xn) + tanhf(a2 * st);
        }
        qv = st;
    }
    {
        unsigned short* A1g = LDSH;
        const int bs = RA_OFF + col * BDS4;
        const int rsel = q >> 1, wo = (q & 1) * 8;
        __builtin_amdgcn_s_setprio(1);
        for (int p = wid * 9; p < wid * 9 + 9; p++) {
            int y = p / 6, x = p % 6;
            int ab1 = bs + ((y + rsel) * 8 + x) * 4 + wo;
            int ab2 = bs + ((y + 2) * 8 + x) * 4 + wo;
            union { h8 v; h4 h[2]; } a1v, a2v;
            a1v.h[0] = *(const h4*)&LDSH[ab1];
            a1v.h[1] = *(const h4*)&LDSH[ab1 + 4];
            a2v.h[0] = *(const h4*)&LDSH[ab2];
            a2v.h[1] = *(const h4*)&LDSH[ab2 + 4];
            f32x4 c = MFMA16(a1v.v, w1r0, ZERO4);
            c = MFMA16(a2v.v, w1r1, c);
            #pragma unroll
            for (int r = 0; r < 4; r++)
                A1g[(q * 4 + r) * A1S + p * 16 + col] =
                    f2h(fmaxf(c[r] + b1v, 0.f));
        }
        __builtin_amdgcn_s_setprio(0);
    }
    __syncthreads();

    // ---- 3. stage g1 from registers (no HBM latency here) ----
    {
        int ss = tid / 27, r27 = tid - ss * 27, f0 = r27 * 4;
        #pragma unroll
        for (int j = 0; j < 4; j++) {
            int f = f0 + j, ch = f / 36, p = f - ch * 36;
            LDSH[RA_OFF + ss * BDS4 + ((p / 6 + 1) * 8 + (p % 6) + 1) * 4 + ch] =
                f2h(v1a[j]);
        }
        if (tid < 176) {
            int e4 = tid + 256;
            int ss2 = e4 / 27, r2 = e4 - ss2 * 27, f02 = r2 * 4;
            #pragma unroll
            for (int j = 0; j < 4; j++) {
                int f = f02 + j, ch = f / 36, p = f - ch * 36;
                LDSH[RA_OFF + ss2 * BDS4 + ((p / 6 + 1) * 8 + (p % 6) + 1) * 4 + ch] =
                    f2h(v1b[j]);
            }
        }
    }
    __syncthreads();

    // ---- 4. conv1 g1 ----
    {
        unsigned short* A1g = LDSH + 9856;
        const int bs = RA_OFF + col * BDS4;
        const int rsel = q >> 1, wo = (q & 1) * 8;
        __builtin_amdgcn_s_setprio(1);
        for (int p = wid * 9; p < wid * 9 + 9; p++) {
            int y = p / 6, x = p % 6;
            int ab1 = bs + ((y + rsel) * 8 + x) * 4 + wo;
            int ab2 = bs + ((y + 2) * 8 + x) * 4 + wo;
            union { h8 v; h4 h[2]; } a1v, a2v;
            a1v.h[0] = *(const h4*)&LDSH[ab1];
            a1v.h[1] = *(const h4*)&LDSH[ab1 + 4];
            a2v.h[0] = *(const h4*)&LDSH[ab2];
            a2v.h[1] = *(const h4*)&LDSH[ab2 + 4];
            f32x4 c = MFMA16(a1v.v, w1r0, ZERO4);
            c = MFMA16(a2v.v, w1r1, c);
            #pragma unroll
            for (int r = 0; r < 4; r++)
                A1g[(q * 4 + r) * A1S + p * 16 + col] =
                    f2h(fmaxf(c[r] + b1v, 0.f));
        }
        __builtin_amdgcn_s_setprio(0);
    }
    __syncthreads();

    // ---- 5. conv2: full-K paired-tap MFMAs (r24-validated) ----
    f32x4 pooled2[9];
    #pragma unroll
    for (int pp = 0; pp < 9; pp++) pooled2[pp] = ZERO4;
    {
        h8 Wp01[3], Wp12[3], Ws2[3];
        #pragma unroll
        for (int d = 0; d < 3; d++) {
            Wp01[d] = ((const h8*)w2f)[((0 + d) * 2 + w2) * 64 + lane];
            Wp12[d] = ((const h8*)w2f)[((3 + d) * 2 + w2) * 64 + lane];
            Ws2[d]  = ((const h8*)w2f)[((6 + d) * 2 + w2) * 64 + lane];
        }
        float b2v = b2[w2 * 16 + col];
        const int sA1 = col * A1S;
        const int kho = q * 8;           // full K=32 across position pair

        __builtin_amdgcn_s_setprio(1);
        h8 R[3][6];
        #pragma unroll
        for (int x = 0; x < 6; x++) {
            R[0][x] = *(const h8*)&A1[sA1 + (0 * 6 + x) * 16 + kho];
            R[1][x] = *(const h8*)&A1[sA1 + (1 * 6 + x) * 16 + kho];
        }
        #pragma unroll
        for (int y = 0; y < 6; y++) {
            if (y >= 1 && y <= 4) {
                const int nr = y + 1, slot = nr % 3;
                #pragma unroll
                for (int x = 0; x < 6; x++)
                    R[slot][x] = *(const h8*)&A1[sA1 + (nr * 6 + x) * 16 + kho];
            }
            f32x4 acc[6];
            #pragma unroll
            for (int x = 0; x < 6; x++) acc[x] = ZERO4;
            #pragma unroll
            for (int dy = -1; dy <= 1; dy++) {
                const int ry = y + dy;
                if (ry < 0 || ry > 5) continue;
                const int slot = ry % 3, di = dy + 1;
                acc[0] = MFMA16(R[slot][0], Wp12[di], acc[0]);
                #pragma unroll
                for (int x = 1; x < 5; x++) {
                    acc[x] = MFMA16(R[slot][x - 1], Wp01[di], acc[x]);
                    acc[x] = MFMA16(R[slot][x + 1], Ws2[di], acc[x]);
                }
                acc[5] = MFMA16(R[slot][4], Wp01[di], acc[5]);
            }
            const int pr = y >> 1;
            #pragma unroll
            for (int px = 0; px < 3; px++)
                #pragma unroll
                for (int xx = 0; xx < 2; xx++)
                    #pragma unroll
                    for (int r = 0; r < 4; r++)
                        pooled2[pr * 3 + px][r] =
                            fmaxf(pooled2[pr * 3 + px][r],
                                  acc[px * 2 + xx][r] + b2v);
        }
        __builtin_amdgcn_s_setprio(0);
    }
    __syncthreads();   // all A1 reads (block-wide) done before A2 overlays
    #pragma unroll
    for (int pp = 0; pp < 9; pp++)
        #pragma unroll
        for (int r = 0; r < 4; r++)
            A2[(q * 4 + r) * A2S + pp * 32 + w2 * 16 + col] =
                f2h(pooled2[pp][r]);
    __syncthreads();

    // ---- 6. conv3 -> registers (otp = w2) ----
    f32x4 c3a[9], c3b[9];
    {
        const int otp = w2;
        const int sA2 = col * A2S;
        h8 W3r[18];
        #pragma unroll
        for (int f = 0; f < 18; f++)
            W3r[f] = ((const h8*)w3f)[(otp * 18 + f) * 64 + lane];
        __builtin_amdgcn_s_setprio(1);
        #pragma unroll
        for (int p = 0; p < 9; p++) {
            const int y = p / 3, x = p % 3;
            f32x4 acc0 = ZERO4, acc1 = ZERO4;
            #pragma unroll
            for (int t = 0; t < 9; t++) {
                const int sy = y + t / 3 - 1, sx = x + t % 3 - 1;
                if (sy < 0 || sy >= 3 || sx < 0 || sx >= 3) continue;
                h8 a = *(const h8*)&A2[sA2 + (sy * 3 + sx) * 32 + q * 8];
                acc0 = MFMA16(a, W3r[t * 2 + 0], acc0);
                acc1 = MFMA16(a, W3r[t * 2 + 1], acc1);
            }
            c3a[p] = acc0; c3b[p] = acc1;
        }
        __builtin_amdgcn_s_setprio(0);
    }
    __syncthreads();   // all A2 reads done before FT overlays region

    // ---- 7. write FT [p][oc] + quantum + zero tail cols 584..615 (FULL) ----
    {
        const int otp = w2;
        float b3v0 = b3[(otp * 2 + 0) * 16 + col];
        float b3v1 = b3[(otp * 2 + 1) * 16 + col];
        int oc0 = (otp * 2 + 0) * 16 + col, oc1 = (otp * 2 + 1) * 16 + col;
        #pragma unroll
        for (int p = 0; p < 9; p++)
            #pragma unroll
            for (int r = 0; r < 4; r++) {
                int row = g * 16 + q * 4 + r;
                LDSH[row * FTS + p * 64 + oc0] = f2h(fmaxf(c3a[p][r] + b3v0, 0.f));
                LDSH[row * FTS + p * 64 + oc1] = f2h(fmaxf(c3b[p][r] + b3v1, 0.f));
            }
        {
            int gq = tid >> 7, ss2 = (tid >> 3) & 15, qq = tid & 7;
            LDSH[(gq * 16 + ss2) * FTS + 576 + qq] = f2h(qv);
        }
        for (int e = tid; e < 1024; e += 256)
            LDSH[(e >> 5) * FTS + 584 + (e & 31)] = 0;
    }
    __syncthreads();

    // ---- 8. heads L1: K=608 (19 kk), wave does nt-tiles wid*3..+2, both mt ----
    {
        f32x4 acc[2][3];
        #pragma unroll
        for (int mt = 0; mt < 2; mt++)
            #pragma unroll
            for (int nt = 0; nt < 3; nt++) acc[mt][nt] = ZERO4;
        const h8* wp1 = (const h8*)w1hd;
        const int ntb = wid * 3;
        __builtin_amdgcn_s_setprio(1);
        for (int kk = 0; kk < 19; kk++) {
            h8 a0 = *(const h8*)&LDSH[col * FTS + kk * 32 + q * 8];
            h8 a1 = *(const h8*)&LDSH[(16 + col) * FTS + kk * 32 + q * 8];
            h8 b[3];
            #pragma unroll
            for (int nt = 0; nt < 3; nt++)
                b[nt] = wp1[(kk * 12 + ntb + nt) * 64 + lane];
            #pragma unroll
            for (int nt = 0; nt < 3; nt++) {
                acc[0][nt] = MFMA16(a0, b[nt], acc[0][nt]);
                acc[1][nt] = MFMA16(a1, b[nt], acc[1][nt]);
            }
        }
        __builtin_amdgcn_s_setprio(0);
        #pragma unroll
        for (int nt = 0; nt < 3; nt++) {
            int ntg = ntb + nt;
            float bv = (ntg < 8) ? ptb1[ntg * 16 + col] : cfb1[(ntg - 8) * 16 + col];
            #pragma unroll
            for (int mt = 0; mt < 2; mt++)
                #pragma unroll
                for (int r = 0; r < 4; r++)
                    Hb[(mt * 16 + q * 4 + r) * HSH + ntg * 16 + col] =
                        f2h(fmaxf(acc[mt][nt][r] + bv, 0.f));
        }
    }
    __syncthreads();

    // ---- 9. heads L2: nt = wid, both mt; output -> dead FT region (base 0,
    //      stride HSH) so Hb is never overwritten: no pre-write barrier ----
    {
        f32x4 acc2[2];
        acc2[0] = ZERO4; acc2[1] = ZERO4;
        const h8* wp2 = (const h8*)w2hd;
        const int nt2 = wid;
        #pragma unroll
        for (int kk = 0; kk < 4; kk++) {
            h8 a0 = *(const h8*)&Hb[col * HSH + kk * 32 + q * 8];
            h8 a1 = *(const h8*)&Hb[(16 + col) * HSH + kk * 32 + q * 8];
            h8 b = wp2[(kk * 4 + nt2) * 64 + lane];
            acc2[0] = MFMA16(a0, b, acc2[0]);
            acc2[1] = MFMA16(a1, b, acc2[1]);
        }
        float bv2 = ptb2[nt2 * 16 + col];
        #pragma unroll
        for (int mt = 0; mt < 2; mt++)
            #pragma unroll
            for (int r = 0; r < 4; r++)
                LDSH[(mt * 16 + q * 4 + r) * HSH + nt2 * 16 + col] =
                    f2h(fmaxf(acc2[mt][r] + bv2, 0.f));
    }
    __syncthreads();

    // ---- 10. heads L3 + epilogue: waves 0,1 handle mt = wid ----
    if (wid < 2) {
        const int mt = wid;
        f32x4 a3 = ZERO4;
        #pragma unroll
        for (int kk = 0; kk < 4; kk++) {
            // kk 0,1: pt-L2 output (FT region); kk 2,3: cf-L1 output (Hb)
            h8 a = (kk < 2)
                ? *(const h8*)&LDSH[(mt * 16 + col) * HSH + kk * 32 + q * 8]
                : *(const h8*)&Hb[(mt * 16 + col) * HSH + kk * 32 + 64 + q * 8];
            h8 b = ((const h8*)w3hd)[kk * 64 + lane];
            a3 = MFMA16(a, b, a3);
        }
        if (col < 3) {
            float bv = (col < 2) ? ptb3[col] : cfb2[0];
            #pragma unroll
            for (int r = 0; r < 4; r++)
                O[(mt * 16 + q * 4 + r) * 4 + col] = a3[r] + bv;
        }
        if (lane < 16) {
            int s = mt * 16 + lane;
            float l0 = O[s * 4 + 0], l1 = O[s * 4 + 1], l2 = O[s * 4 + 2];
            float m = fmaxf(l0, l1);
            float e0 = expf(l0 - m), e1 = expf(l1 - m);
            float inv = 1.f / (e0 + e1);
            float* op = out + (gg0 + s) * 3;
            op[0] = e0 * inv;
            op[1] = e1 * inv;
            op[2] = 1.f / (1.f + expf(-l2));
        }
    }
}

extern "C" void kernel_launch(void* const* d_in, const int* in_sizes, int n_in,
                              void* d_out, int out_size, void* d_ws, size_t ws_size,
                              hipStream_t stream) {
    const float* board = (const float*)d_in[0];
    const float* c1w  = (const float*)d_in[2];
    const float* c1b  = (const float*)d_in[3];
    const float* c2w  = (const float*)d_in[4];
    const float* c2b  = (const float*)d_in[5];
    const float* c3w  = (const float*)d_in[6];
    const float* c3b  = (const float*)d_in[7];
    const float* qp   = (const float*)d_in[8];
    const float* ptw1 = (const float*)d_in[9];
    const float* ptb1 = (const float*)d_in[10];
    const float* ptw2 = (const float*)d_in[11];
    const float* ptb2 = (const float*)d_in[12];
    const float* ptw3 = (const float*)d_in[13];
    const float* ptb3 = (const float*)d_in[14];
    const float* cfw1 = (const float*)d_in[15];
    const float* cfb1 = (const float*)d_in[16];
    const float* cfw2 = (const float*)d_in[17];
    const float* cfb2 = (const float*)d_in[18];
    float* out = (float*)d_out;

    int Btot = in_sizes[0] / 108;          // 65536

    unsigned short* w1f   = (unsigned short*)d_ws;
    unsigned short* w2f   = (unsigned short*)((char*)d_ws + 2048);
    unsigned short* w3f   = (unsigned short*)((char*)d_ws + 20480);
    unsigned short* w1hd  = (unsigned short*)((char*)d_ws + 57344);
    unsigned short* w2hd  = (unsigned short*)((char*)d_ws + 290816);
    unsigned short* w3hd  = (unsigned short*)((char*)d_ws + 307200);

    hipLaunchKernelGGL(k_prep, dim3(256), dim3(256), 0, stream,
                       c1w, c2w, c3w, ptw1, cfw1, ptw2, ptw3, cfw2,
                       w1f, w2f, w3f, w1hd, w2hd, w3hd);
    hipLaunchKernelGGL(k_fused, dim3(Btot / 32), dim3(256), 0, stream,
                       board, c1b, c2b, c3b, qp, w1f, w2f, w3f,
                       w1hd, w2hd, w3hd, ptb1, ptb2, ptb3, cfb1, cfb2, out);
}